// Round 7
// baseline (202.023 us; speedup 1.0000x reference)
//
#include <hip/hip_runtime.h>
#include <hip/hip_bf16.h>

#define N_PTS   131072
#define N_FEATS 1000
#define FDIM    64
#define HID     128
#define NCHUNK  32          // 32 K-chunks of 32 features (padded 1000 -> 1024)
#define PI_F    3.14159265358979f
#define L2E     1.44269504f

typedef short  short8  __attribute__((ext_vector_type(8)));   // bf16 A/B frag (4 VGPRs)
typedef float  floatx4 __attribute__((ext_vector_type(4)));   // C/D frag
typedef float  f4      __attribute__((ext_vector_type(4)));

// ---- bf16 helpers ----
__device__ __forceinline__ unsigned int packbf2(float a, float b) {
    float2 t; t.x = a; t.y = b;
    __hip_bfloat162 h = __float22bfloat162_rn(t);
    union { __hip_bfloat162 hh; unsigned int u; } cv; cv.hh = h;
    return cv.u;
}
__device__ __forceinline__ unsigned short f2bf(float f) {      // RNE, 1 v_cvt_pk
    return (unsigned short)packbf2(f, f);
}
__device__ __forceinline__ float bf2f(unsigned short h) {
    return __uint_as_float(((unsigned int)h) << 16);
}
__device__ __forceinline__ f4 min4(f4 a, f4 b) {
    f4 r;
    r[0] = fminf(a[0], b[0]); r[1] = fminf(a[1], b[1]);
    r[2] = fminf(a[2], b[2]); r[3] = fminf(a[3], b[3]);
    return r;
}
// shifted squared distance: t = |loc|^2 - 2 x.loc  (d2 = t + |x|^2)
// MUST be used identically in pass 1 and pass 2 so rounding matches exactly.
__device__ __forceinline__ f4 shifted_d2(f4 lx, f4 ly, f4 lz, f4 sl,
                                         float x0, float x1, float x2) {
    f4 d = lx*x0; d += ly*x1; d += lz*x2;       // mul + fma + fma
    return sl - 2.f*d;                          // fma(d, -2, sl)
}

// ---------------- fused prep ----------------
// fvB (direct-load fragment layout):
//   i = cq*512 + n*8 + j ; f = (cq>>2)*32 + (cq&3)*8 + j ; value = fv[f][n]
// WB: 16 stages (4 layers x 4 quarters) of 8KB, lane-indexed:
//   r = ((((L*4+q)*2 + nt)*4 + c)*64 + lane)*8 + j
//   value = W_L[n=(q*2+nt)*16+(lane&15)][k=c*32+(lane>>4)*8+j], layer0 K padded 100->128
// LX/LY/LZ/SL [1024], pads at 1e9 (never the min distance)
__global__ void prep_all(const float* __restrict__ locs, const float* __restrict__ fv,
                         const float* __restrict__ W0, const float* __restrict__ W1,
                         const float* __restrict__ W2, const float* __restrict__ W3,
                         float* __restrict__ LX, float* __restrict__ LY, float* __restrict__ LZ,
                         float* __restrict__ SL,
                         unsigned short* __restrict__ fvB, unsigned short* __restrict__ WB)
{
    int i = blockIdx.x * 256 + threadIdx.x;
    if (i < 65536) {
        int j = i & 7, n = (i >> 3) & 63, cq = i >> 9;
        int f = (cq >> 2) * 32 + (cq & 3) * 8 + j;
        float v = (f < N_FEATS) ? fv[f*FDIM + n] : 0.f;
        fvB[i] = f2bf(v);
    } else if (i < 131072) {
        int r = i - 65536;
        int j = r & 7, lane = (r >> 3) & 63, c = (r >> 9) & 3;
        int nt = (r >> 11) & 1, q = (r >> 12) & 3, L = r >> 14;
        int n = (q*2 + nt)*16 + (lane & 15);
        int k = c*32 + (lane >> 4)*8 + j;
        const float* W = (L == 0) ? W0 : (L == 1) ? W1 : (L == 2) ? W2 : W3;
        int Kin = (L == 0) ? 100 : 128;
        float v = (k < Kin) ? W[n*Kin + k] : 0.f;
        WB[r] = f2bf(v);
    } else if (i < 132096) {
        int t = i - 131072;
        bool val = t < N_FEATS;
        float lx = val ? locs[t*3+0] : 1e9f;
        float ly = val ? locs[t*3+1] : 1e9f;
        float lz = val ? locs[t*3+2] : 1e9f;
        LX[t] = lx; LY[t] = ly; LZ[t] = lz;
        SL[t] = lx*lx + ly*ly + lz*lz;          // 3e18 for pads -> never min
    }
}

// ---------------- main fused kernel ----------------
// 4 waves/block, 32 points/wave (two 16-pt A-tiles), zero __syncthreads,
// all B-operands direct from L2-resident workspace (R3-R6: staging is neutral).
// launch_bounds(256,4): retry of R5's failed 4-blocks/CU, now with a leaner
// arch-VGPR body (chunk-31 peeled out of the hot loop, clamp removed) so the
// allocator can fit [arch + acc] <= 128 without the R5 spill. Grid 1024 =
// exactly 4 blocks/CU x 256 CUs -> no tail round. Tripwire: WRITE_SIZE.
__global__ __launch_bounds__(256, 4)
void afvsrn_mfma(const float* __restrict__ x,
                 const float* __restrict__ LX, const float* __restrict__ LY,
                 const float* __restrict__ LZ, const float* __restrict__ SL,
                 const unsigned short* __restrict__ fvB,
                 const unsigned short* __restrict__ WB,
                 const float* __restrict__ b0, const float* __restrict__ b1,
                 const float* __restrict__ b2, const float* __restrict__ b3,
                 const float* __restrict__ W4, const float* __restrict__ b4,
                 float* __restrict__ out)
{
    __shared__ unsigned short act[128 * 136];                 // [128 pts][128+8 pad] bf16

    const int lane = threadIdx.x & 63;
    const int wv   = threadIdx.x >> 6;
    const int ptl  = lane & 15;                // A-frag row m / C-frag col n
    const int quad = lane >> 4;                // A/B-frag k-group, C-frag row-group
    const int ptbase = blockIdx.x * 128 + wv * 32;

    const float xA0 = x[(ptbase + ptl)*3 + 0];
    const float xA1 = x[(ptbase + ptl)*3 + 1];
    const float xA2 = x[(ptbase + ptl)*3 + 2];
    const float xB0 = x[(ptbase + 16 + ptl)*3 + 0];
    const float xB1 = x[(ptbase + 16 + ptl)*3 + 1];
    const float xB2 = x[(ptbase + 16 + ptl)*3 + 2];
    const float AA  = xA0*xA0 + xA1*xA1 + xA2*xA2;
    const float AB  = xB0*xB0 + xB1*xB1 + xB2*xB2;

    const f4* LX4 = (const f4*)LX;
    const f4* LY4 = (const f4*)LY;
    const f4* LZ4 = (const f4*)LZ;
    const f4* SL4 = (const f4*)SL;

    // ---------- pass 1: min shifted-d2 for both tiles (no transcendentals) ----------
    f4 mnA = {1e30f, 1e30f, 1e30f, 1e30f};
    f4 mnB = {1e30f, 1e30f, 1e30f, 1e30f};
    #pragma unroll 2
    for (int c = 0; c < NCHUNK; ++c) {
        int g = c*8 + quad*2;
        #pragma unroll
        for (int h = 0; h < 2; ++h) {
            f4 lx = LX4[g+h], ly = LY4[g+h], lz = LZ4[g+h], sl = SL4[g+h];
            mnA = min4(mnA, shifted_d2(lx, ly, lz, sl, xA0, xA1, xA2));
            mnB = min4(mnB, shifted_d2(lx, ly, lz, sl, xB0, xB1, xB2));
        }
    }
    float mdA = fminf(fminf(mnA[0], mnA[1]), fminf(mnA[2], mnA[3]));
    float mdB = fminf(fminf(mnB[0], mnB[1]), fminf(mnB[2], mnB[3]));
    mdA = fminf(mdA, __shfl_xor(mdA, 16));
    mdA = fminf(mdA, __shfl_xor(mdA, 32));
    mdB = fminf(mdB, __shfl_xor(mdB, 16));
    mdB = fminf(mdB, __shfl_xor(mdB, 32));
    // m = max inv_d = rsqrt(min d2). RN add is monotonic, so min over t + A
    // equals min over (t+A): pass-2 arg of rsq is bit-identical for the argmin.
    const float nmA = -__builtin_amdgcn_rsqf(fmaxf(mdA + AA, 1e-12f)) * L2E;
    const float nmB = -__builtin_amdgcn_rsqf(fmaxf(mdB + AB, 1e-12f)) * L2E;

    // ---------- pass 2: p = exp2(fma(inv_d, log2e, nm)); GEMM feats = w @ fv ----
    // No upper clamp on the exp2 arg: for the argmin feature the fma argument is
    // -(rounding error of m*L2E), and that same offset applies to EVERY feature
    // of the point (nm is shared) -> a common factor 2^delta that cancels exactly
    // in the softmax normalization. ls comes free from an extra MFMA against an
    // all-ones B tile: its C-frag row (quad*4+r) is exactly the point whose linv
    // each lane needs -> no shuffles. Chunk 31 (pad chunk) is peeled below so the
    // hot loop carries no pad cndmask.
    const short8 ONES = {0x3F80,0x3F80,0x3F80,0x3F80,0x3F80,0x3F80,0x3F80,0x3F80};
    floatx4 acc2A[4] = {}, acc2B[4] = {};
    floatx4 accLA = {}, accLB = {};
    #pragma unroll 1
    for (int c = 0; c < NCHUNK-1; ++c) {
        // B loads first: independent of the transcendental chains, ~200cy to hide
        const short8* bp = (const short8*)fvB + (c*4 + quad)*64;
        short8 bf0 = bp[ptl];
        short8 bf1 = bp[16 + ptl];
        short8 bf2 = bp[32 + ptl];
        short8 bf3 = bp[48 + ptl];

        const int g = c*8 + quad*2;
        union { short8 v; unsigned int u[4]; } afA, afB;
        #pragma unroll
        for (int h = 0; h < 2; ++h) {
            f4 lx = LX4[g+h], ly = LY4[g+h], lz = LZ4[g+h], sl = SL4[g+h];
            f4 tA = shifted_d2(lx, ly, lz, sl, xA0, xA1, xA2);
            f4 tB = shifted_d2(lx, ly, lz, sl, xB0, xB1, xB2);
            f4 pA, pB;
            #pragma unroll
            for (int e = 0; e < 4; ++e) {
                float ivA = __builtin_amdgcn_rsqf(fmaxf(tA[e] + AA, 1e-12f));
                float ivB = __builtin_amdgcn_rsqf(fmaxf(tB[e] + AB, 1e-12f));
                pA[e] = __builtin_amdgcn_exp2f(fmaf(ivA, L2E, nmA));
                pB[e] = __builtin_amdgcn_exp2f(fmaf(ivB, L2E, nmB));
            }
            afA.u[2*h]   = packbf2(pA[0], pA[1]);
            afA.u[2*h+1] = packbf2(pA[2], pA[3]);
            afB.u[2*h]   = packbf2(pB[0], pB[1]);
            afB.u[2*h+1] = packbf2(pB[2], pB[3]);
        }
        acc2A[0] = __builtin_amdgcn_mfma_f32_16x16x32_bf16(afA.v, bf0, acc2A[0], 0, 0, 0);
        acc2B[0] = __builtin_amdgcn_mfma_f32_16x16x32_bf16(afB.v, bf0, acc2B[0], 0, 0, 0);
        acc2A[1] = __builtin_amdgcn_mfma_f32_16x16x32_bf16(afA.v, bf1, acc2A[1], 0, 0, 0);
        acc2B[1] = __builtin_amdgcn_mfma_f32_16x16x32_bf16(afB.v, bf1, acc2B[1], 0, 0, 0);
        acc2A[2] = __builtin_amdgcn_mfma_f32_16x16x32_bf16(afA.v, bf2, acc2A[2], 0, 0, 0);
        acc2B[2] = __builtin_amdgcn_mfma_f32_16x16x32_bf16(afB.v, bf2, acc2B[2], 0, 0, 0);
        acc2A[3] = __builtin_amdgcn_mfma_f32_16x16x32_bf16(afA.v, bf3, acc2A[3], 0, 0, 0);
        acc2B[3] = __builtin_amdgcn_mfma_f32_16x16x32_bf16(afB.v, bf3, acc2B[3], 0, 0, 0);
        accLA = __builtin_amdgcn_mfma_f32_16x16x32_bf16(afA.v, ONES, accLA, 0, 0, 0);
        accLB = __builtin_amdgcn_mfma_f32_16x16x32_bf16(afB.v, ONES, accLB, 0, 0, 0);
    }
    {   // ---------- peeled chunk 31: features 992..1023, only quad 0 is real ----------
        // nm = -inf on pad lanes: t+A ~ 3e18 -> rsq tiny -> fma(tiny,L2E,-inf) = -inf
        // -> exp2 = exactly 0, so pads contribute nothing to feats or ls.
        const int c = NCHUNK-1;
        const short8* bp = (const short8*)fvB + (c*4 + quad)*64;
        short8 bf0 = bp[ptl];
        short8 bf1 = bp[16 + ptl];
        short8 bf2 = bp[32 + ptl];
        short8 bf3 = bp[48 + ptl];

        const int g = c*8 + quad*2;
        const float nmAe = (quad != 0) ? -__builtin_inff() : nmA;
        const float nmBe = (quad != 0) ? -__builtin_inff() : nmB;
        union { short8 v; unsigned int u[4]; } afA, afB;
        #pragma unroll
        for (int h = 0; h < 2; ++h) {
            f4 lx = LX4[g+h], ly = LY4[g+h], lz = LZ4[g+h], sl = SL4[g+h];
            f4 tA = shifted_d2(lx, ly, lz, sl, xA0, xA1, xA2);
            f4 tB = shifted_d2(lx, ly, lz, sl, xB0, xB1, xB2);
            f4 pA, pB;
            #pragma unroll
            for (int e = 0; e < 4; ++e) {
                float ivA = __builtin_amdgcn_rsqf(fmaxf(tA[e] + AA, 1e-12f));
                float ivB = __builtin_amdgcn_rsqf(fmaxf(tB[e] + AB, 1e-12f));
                pA[e] = __builtin_amdgcn_exp2f(fmaf(ivA, L2E, nmAe));
                pB[e] = __builtin_amdgcn_exp2f(fmaf(ivB, L2E, nmBe));
            }
            afA.u[2*h]   = packbf2(pA[0], pA[1]);
            afA.u[2*h+1] = packbf2(pA[2], pA[3]);
            afB.u[2*h]   = packbf2(pB[0], pB[1]);
            afB.u[2*h+1] = packbf2(pB[2], pB[3]);
        }
        acc2A[0] = __builtin_amdgcn_mfma_f32_16x16x32_bf16(afA.v, bf0, acc2A[0], 0, 0, 0);
        acc2B[0] = __builtin_amdgcn_mfma_f32_16x16x32_bf16(afB.v, bf0, acc2B[0], 0, 0, 0);
        acc2A[1] = __builtin_amdgcn_mfma_f32_16x16x32_bf16(afA.v, bf1, acc2A[1], 0, 0, 0);
        acc2B[1] = __builtin_amdgcn_mfma_f32_16x16x32_bf16(afB.v, bf1, acc2B[1], 0, 0, 0);
        acc2A[2] = __builtin_amdgcn_mfma_f32_16x16x32_bf16(afA.v, bf2, acc2A[2], 0, 0, 0);
        acc2B[2] = __builtin_amdgcn_mfma_f32_16x16x32_bf16(afB.v, bf2, acc2B[2], 0, 0, 0);
        acc2A[3] = __builtin_amdgcn_mfma_f32_16x16x32_bf16(afA.v, bf3, acc2A[3], 0, 0, 0);
        acc2B[3] = __builtin_amdgcn_mfma_f32_16x16x32_bf16(afB.v, bf3, acc2B[3], 0, 0, 0);
        accLA = __builtin_amdgcn_mfma_f32_16x16x32_bf16(afA.v, ONES, accLA, 0, 0, 0);
        accLB = __builtin_amdgcn_mfma_f32_16x16x32_bf16(afB.v, ONES, accLB, 0, 0, 0);
    }

    float linvA[4], linvB[4];
    #pragma unroll
    for (int r = 0; r < 4; ++r) {
        linvA[r] = __builtin_amdgcn_rcpf(accLA[r]);
        linvB[r] = __builtin_amdgcn_rcpf(accLB[r]);
    }

    // ---------- stage y = [PE(36) | feats(64) | zero pad to 128] for both tiles ----
    const int myrowA = (wv*32 + ptl) * 136;
    const int myrowB = (wv*32 + 16 + ptl) * 136;
    *(short8*)&act[myrowA + 96 + quad*8] = (short8)0;
    *(short8*)&act[myrowB + 96 + quad*8] = (short8)0;

    #pragma unroll
    for (int i = 0; i < 9; ++i) {
        int k = quad*9 + i;
        int d = k / 12, r12 = k % 12, l = r12 % 6;
        float fr = PI_F * (float)(1 << l);
        float xvA = (d == 0) ? xA0 : (d == 1) ? xA1 : xA2;
        float xvB = (d == 0) ? xB0 : (d == 1) ? xB1 : xB2;
        float vA = (r12 < 6) ? __sinf(xvA * fr) : __cosf(xvA * fr);
        float vB = (r12 < 6) ? __sinf(xvB * fr) : __cosf(xvB * fr);
        act[myrowA + k] = f2bf(vA);
        act[myrowB + k] = f2bf(vB);
    }

    #pragma unroll
    for (int nt = 0; nt < 4; ++nt)
        #pragma unroll
        for (int r = 0; r < 4; ++r) {
            act[(wv*32 + quad*4 + r)*136 + 36 + nt*16 + ptl]      = f2bf(acc2A[nt][r] * linvA[r]);
            act[(wv*32 + 16 + quad*4 + r)*136 + 36 + nt*16 + ptl] = f2bf(acc2B[nt][r] * linvB[r]);
        }

    // ---------- MLP layers 0..3 via MFMA, weights direct from L2 (no barriers) ----
    short8 aA[4], aB[4];
    #pragma unroll 1
    for (int t = 0; t < 16; ++t) {
        const int L = t >> 2, q = t & 3;
        if (q == 0) {      // new layer: capture input activations (wave-private rows)
            #pragma unroll
            for (int c = 0; c < 4; ++c) {
                aA[c] = *(const short8*)&act[myrowA + c*32 + quad*8];
                aB[c] = *(const short8*)&act[myrowB + c*32 + quad*8];
            }
        }
        const float* bL = (L == 0) ? b0 : (L == 1) ? b1 : (L == 2) ? b2 : b3;
        const short8* bp = (const short8*)WB + t*512;   // 8KB quarter-layer stage
        #pragma unroll
        for (int nt = 0; nt < 2; ++nt) {
            floatx4 accA = {}, accB = {};
            #pragma unroll
            for (int c = 0; c < 4; ++c) {
                short8 bw = bp[(nt*4 + c)*64 + lane];
                accA = __builtin_amdgcn_mfma_f32_16x16x32_bf16(aA[c], bw, accA, 0, 0, 0);
                accB = __builtin_amdgcn_mfma_f32_16x16x32_bf16(aB[c], bw, accB, 0, 0, 0);
            }
            const int col = (q*2 + nt)*16 + ptl;
            const float bias = bL[col];
            #pragma unroll
            for (int r = 0; r < 4; ++r) {
                float hA = accA[r] + bias;
                float hB = accB[r] + bias;
                float sA = __sinf(hA);
                float sB = __sinf(hB);
                hA = 0.5f*hA + sA*sA;                   // SnakeAlt
                hB = 0.5f*hB + sB*sB;
                act[(wv*32 + quad*4 + r)*136 + col]      = f2bf(hA);
                act[(wv*32 + 16 + quad*4 + r)*136 + col] = f2bf(hB);
            }
        }
    }

    // ---------- layer 4: 128 -> 1 (W4 loads shared across both tiles) ----------
    float oA = 0.f, oB = 0.f;
    #pragma unroll
    for (int s = 0; s < 4; ++s) {
        short8 avA = *(const short8*)&act[myrowA + quad*32 + s*8];
        short8 avB = *(const short8*)&act[myrowB + quad*32 + s*8];
        const floatx4* wp = (const floatx4*)W4 + (quad*32 + s*8)/4;
        floatx4 w0 = wp[0], w1 = wp[1];
        oA = fmaf(bf2f((unsigned short)avA[0]), w0[0], oA);
        oB = fmaf(bf2f((unsigned short)avB[0]), w0[0], oB);
        oA = fmaf(bf2f((unsigned short)avA[1]), w0[1], oA);
        oB = fmaf(bf2f((unsigned short)avB[1]), w0[1], oB);
        oA = fmaf(bf2f((unsigned short)avA[2]), w0[2], oA);
        oB = fmaf(bf2f((unsigned short)avB[2]), w0[2], oB);
        oA = fmaf(bf2f((unsigned short)avA[3]), w0[3], oA);
        oB = fmaf(bf2f((unsigned short)avB[3]), w0[3], oB);
        oA = fmaf(bf2f((unsigned short)avA[4]), w1[0], oA);
        oB = fmaf(bf2f((unsigned short)avB[4]), w1[0], oB);
        oA = fmaf(bf2f((unsigned short)avA[5]), w1[1], oA);
        oB = fmaf(bf2f((unsigned short)avB[5]), w1[1], oB);
        oA = fmaf(bf2f((unsigned short)avA[6]), w1[2], oA);
        oB = fmaf(bf2f((unsigned short)avB[6]), w1[2], oB);
        oA = fmaf(bf2f((unsigned short)avA[7]), w1[3], oA);
        oB = fmaf(bf2f((unsigned short)avB[7]), w1[3], oB);
    }
    oA += __shfl_xor(oA, 16);
    oA += __shfl_xor(oA, 32);
    oB += __shfl_xor(oB, 16);
    oB += __shfl_xor(oB, 32);
    if (quad == 0) {
        float bb = b4[0];
        out[ptbase + ptl]      = oA + bb;
        out[ptbase + 16 + ptl] = oB + bb;
    }
}

extern "C" void kernel_launch(void* const* d_in, const int* in_sizes, int n_in,
                              void* d_out, int out_size, void* d_ws, size_t ws_size,
                              hipStream_t stream)
{
    const float* x  = (const float*)d_in[0];
    const float* lc = (const float*)d_in[1];
    const float* fv = (const float*)d_in[2];
    const float* W0 = (const float*)d_in[3];
    const float* b0 = (const float*)d_in[4];
    const float* W1 = (const float*)d_in[5];
    const float* b1 = (const float*)d_in[6];
    const float* W2 = (const float*)d_in[7];
    const float* b2 = (const float*)d_in[8];
    const float* W3 = (const float*)d_in[9];
    const float* b3 = (const float*)d_in[10];
    const float* W4 = (const float*)d_in[11];
    const float* b4 = (const float*)d_in[12];

    char* ws = (char*)d_ws;
    float*          LXp = (float*)(ws + 0);
    float*          LYp = (float*)(ws + 4096);
    float*          LZp = (float*)(ws + 8192);
    float*          SLp = (float*)(ws + 12288);
    unsigned short* fvB = (unsigned short*)(ws + 16384);            // 128 KB
    unsigned short* WB  = (unsigned short*)(ws + 16384 + 131072);   // 128 KB

    prep_all<<<dim3(516), dim3(256), 0, stream>>>(lc, fv, W0, W1, W2, W3,
                                                  LXp, LYp, LZp, SLp, fvB, WB);

    afvsrn_mfma<<<dim3(N_PTS/128), dim3(256), 0, stream>>>(
        x, LXp, LYp, LZp, SLp, fvB, WB, b0, b1, b2, b3, W4, b4, (float*)d_out);
}

// Round 8
// 193.241 us; speedup vs baseline: 1.0454x; 1.0454x over previous
//
#include <hip/hip_runtime.h>
#include <hip/hip_bf16.h>

#define N_PTS   131072
#define N_FEATS 1000
#define FDIM    64
#define HID     128
#define NCHUNK  32          // 32 K-chunks of 32 features (padded 1000 -> 1024)
#define PI_F    3.14159265358979f
#define L2E     1.44269504f

typedef short  short8  __attribute__((ext_vector_type(8)));   // bf16 A/B frag (4 VGPRs)
typedef float  floatx4 __attribute__((ext_vector_type(4)));   // C/D frag
typedef float  f4      __attribute__((ext_vector_type(4)));

// ---- bf16 helpers ----
__device__ __forceinline__ unsigned int packbf2(float a, float b) {
    float2 t; t.x = a; t.y = b;
    __hip_bfloat162 h = __float22bfloat162_rn(t);
    union { __hip_bfloat162 hh; unsigned int u; } cv; cv.hh = h;
    return cv.u;
}
__device__ __forceinline__ unsigned short f2bf(float f) {      // RNE, 1 v_cvt_pk
    return (unsigned short)packbf2(f, f);
}
__device__ __forceinline__ float bf2f(unsigned short h) {
    return __uint_as_float(((unsigned int)h) << 16);
}
// 3-input elementwise min; clang fuses nested fminf to v_min3_f32 on gfx9+
__device__ __forceinline__ f4 min3_4(f4 a, f4 b, f4 c) {
    f4 r;
    r[0] = fminf(fminf(a[0], b[0]), c[0]);
    r[1] = fminf(fminf(a[1], b[1]), c[1]);
    r[2] = fminf(fminf(a[2], b[2]), c[2]);
    r[3] = fminf(fminf(a[3], b[3]), c[3]);
    return r;
}
// shifted squared distance: t = |loc|^2 - 2 x.loc  (d2 = t + |x|^2)
// l2* hold -2*loc (precomputed in prep) -> pure 3-FMA chain (was mul+3fma).
// MUST be used identically in pass 1 and pass 2 so rounding matches exactly.
__device__ __forceinline__ f4 shifted_d2(f4 l2x, f4 l2y, f4 l2z, f4 sl,
                                         float x0, float x1, float x2) {
    f4 t = sl;
    t = l2z*x2 + t;        // fma
    t = l2y*x1 + t;        // fma
    t = l2x*x0 + t;        // fma
    return t;
}

// ---------------- fused prep ----------------
// fvB (direct-load fragment layout):
//   i = cq*512 + n*8 + j ; f = (cq>>2)*32 + (cq&3)*8 + j ; value = fv[f][n]
// WB: 16 stages (4 layers x 4 quarters) of 8KB, lane-indexed:
//   r = ((((L*4+q)*2 + nt)*4 + c)*64 + lane)*8 + j
//   value = W_L[n=(q*2+nt)*16+(lane&15)][k=c*32+(lane>>4)*8+j], layer0 K padded 100->128
// LX/LY/LZ hold -2*loc (3-FMA dot); SL = |loc|^2 from RAW coords.
// Pads at loc=1e9 -> SL=3e18 dominates t -> never the min distance.
__global__ void prep_all(const float* __restrict__ locs, const float* __restrict__ fv,
                         const float* __restrict__ W0, const float* __restrict__ W1,
                         const float* __restrict__ W2, const float* __restrict__ W3,
                         float* __restrict__ LX, float* __restrict__ LY, float* __restrict__ LZ,
                         float* __restrict__ SL,
                         unsigned short* __restrict__ fvB, unsigned short* __restrict__ WB)
{
    int i = blockIdx.x * 256 + threadIdx.x;
    if (i < 65536) {
        int j = i & 7, n = (i >> 3) & 63, cq = i >> 9;
        int f = (cq >> 2) * 32 + (cq & 3) * 8 + j;
        float v = (f < N_FEATS) ? fv[f*FDIM + n] : 0.f;
        fvB[i] = f2bf(v);
    } else if (i < 131072) {
        int r = i - 65536;
        int j = r & 7, lane = (r >> 3) & 63, c = (r >> 9) & 3;
        int nt = (r >> 11) & 1, q = (r >> 12) & 3, L = r >> 14;
        int n = (q*2 + nt)*16 + (lane & 15);
        int k = c*32 + (lane >> 4)*8 + j;
        const float* W = (L == 0) ? W0 : (L == 1) ? W1 : (L == 2) ? W2 : W3;
        int Kin = (L == 0) ? 100 : 128;
        float v = (k < Kin) ? W[n*Kin + k] : 0.f;
        WB[r] = f2bf(v);
    } else if (i < 132096) {
        int t = i - 131072;
        bool val = t < N_FEATS;
        float lx = val ? locs[t*3+0] : 1e9f;
        float ly = val ? locs[t*3+1] : 1e9f;
        float lz = val ? locs[t*3+2] : 1e9f;
        LX[t] = -2.f*lx; LY[t] = -2.f*ly; LZ[t] = -2.f*lz;
        SL[t] = lx*lx + ly*ly + lz*lz;          // 3e18 for pads -> never min
    }
}

// ---------------- main fused kernel ----------------
// 4 waves/block, 32 points/wave (two 16-pt A-tiles), zero __syncthreads,
// all B-operands direct from L2-resident workspace (R3-R6: staging is neutral).
// launch_bounds(256,3): FINAL. R5+R7 both proved (256,4) infeasible: unified
// VGPR+AGPR demand is ~136/wave (72 arch + 64 acc) -> 3 waves/SIMD is this
// algorithm's occupancy; demanding 4 forces arch->64 and hot-loop spill
// (WRITE_SIZE 512->9728 KB). This round shrinks ISSUE COUNT instead:
// -2*loc precompute (3-FMA dot, -25% per dot) + v_min3 pass-1 fusion.
__global__ __launch_bounds__(256, 3)
void afvsrn_mfma(const float* __restrict__ x,
                 const float* __restrict__ LX, const float* __restrict__ LY,
                 const float* __restrict__ LZ, const float* __restrict__ SL,
                 const unsigned short* __restrict__ fvB,
                 const unsigned short* __restrict__ WB,
                 const float* __restrict__ b0, const float* __restrict__ b1,
                 const float* __restrict__ b2, const float* __restrict__ b3,
                 const float* __restrict__ W4, const float* __restrict__ b4,
                 float* __restrict__ out)
{
    __shared__ unsigned short act[128 * 136];                 // [128 pts][128+8 pad] bf16

    const int lane = threadIdx.x & 63;
    const int wv   = threadIdx.x >> 6;
    const int ptl  = lane & 15;                // A-frag row m / C-frag col n
    const int quad = lane >> 4;                // A/B-frag k-group, C-frag row-group
    const int ptbase = blockIdx.x * 128 + wv * 32;

    const float xA0 = x[(ptbase + ptl)*3 + 0];
    const float xA1 = x[(ptbase + ptl)*3 + 1];
    const float xA2 = x[(ptbase + ptl)*3 + 2];
    const float xB0 = x[(ptbase + 16 + ptl)*3 + 0];
    const float xB1 = x[(ptbase + 16 + ptl)*3 + 1];
    const float xB2 = x[(ptbase + 16 + ptl)*3 + 2];
    const float AA  = xA0*xA0 + xA1*xA1 + xA2*xA2;
    const float AB  = xB0*xB0 + xB1*xB1 + xB2*xB2;

    const f4* LX4 = (const f4*)LX;
    const f4* LY4 = (const f4*)LY;
    const f4* LZ4 = (const f4*)LZ;
    const f4* SL4 = (const f4*)SL;

    // ---------- pass 1: min shifted-d2 for both tiles (no transcendentals) ----------
    f4 mnA = {1e30f, 1e30f, 1e30f, 1e30f};
    f4 mnB = {1e30f, 1e30f, 1e30f, 1e30f};
    #pragma unroll 2
    for (int c = 0; c < NCHUNK; ++c) {
        int g = c*8 + quad*2;
        f4 lx0 = LX4[g],   ly0 = LY4[g],   lz0 = LZ4[g],   sl0 = SL4[g];
        f4 lx1 = LX4[g+1], ly1 = LY4[g+1], lz1 = LZ4[g+1], sl1 = SL4[g+1];
        f4 tA0 = shifted_d2(lx0, ly0, lz0, sl0, xA0, xA1, xA2);
        f4 tA1 = shifted_d2(lx1, ly1, lz1, sl1, xA0, xA1, xA2);
        f4 tB0 = shifted_d2(lx0, ly0, lz0, sl0, xB0, xB1, xB2);
        f4 tB1 = shifted_d2(lx1, ly1, lz1, sl1, xB0, xB1, xB2);
        mnA = min3_4(mnA, tA0, tA1);           // v_min3_f32
        mnB = min3_4(mnB, tB0, tB1);
    }
    float mdA = fminf(fminf(mnA[0], mnA[1]), fminf(mnA[2], mnA[3]));
    float mdB = fminf(fminf(mnB[0], mnB[1]), fminf(mnB[2], mnB[3]));
    mdA = fminf(mdA, __shfl_xor(mdA, 16));
    mdA = fminf(mdA, __shfl_xor(mdA, 32));
    mdB = fminf(mdB, __shfl_xor(mdB, 16));
    mdB = fminf(mdB, __shfl_xor(mdB, 32));
    // m = max inv_d = rsqrt(min d2). RN add is monotonic, so min over t + A
    // equals min over (t+A): pass-2 arg of rsq is bit-identical for the argmin.
    const float nmA = -__builtin_amdgcn_rsqf(fmaxf(mdA + AA, 1e-12f)) * L2E;
    const float nmB = -__builtin_amdgcn_rsqf(fmaxf(mdB + AB, 1e-12f)) * L2E;

    // ---------- pass 2: p = exp2(fma(inv_d, log2e, nm)); GEMM feats = w @ fv ----
    // No upper clamp on the exp2 arg: the rounding slack of m*L2E is a COMMON
    // offset across all features of a point (nm shared) -> common factor 2^delta
    // cancels exactly in the softmax normalization. ls comes free from an extra
    // MFMA against an all-ones B tile: its C-frag row (quad*4+r) is exactly the
    // point whose linv each lane needs -> no shuffles. Chunk 31 (pad) peeled.
    const short8 ONES = {0x3F80,0x3F80,0x3F80,0x3F80,0x3F80,0x3F80,0x3F80,0x3F80};
    floatx4 acc2A[4] = {}, acc2B[4] = {};
    floatx4 accLA = {}, accLB = {};
    #pragma unroll 1
    for (int c = 0; c < NCHUNK-1; ++c) {
        // B loads first: independent of the transcendental chains, ~200cy to hide
        const short8* bp = (const short8*)fvB + (c*4 + quad)*64;
        short8 bf0 = bp[ptl];
        short8 bf1 = bp[16 + ptl];
        short8 bf2 = bp[32 + ptl];
        short8 bf3 = bp[48 + ptl];

        const int g = c*8 + quad*2;
        union { short8 v; unsigned int u[4]; } afA, afB;
        #pragma unroll
        for (int h = 0; h < 2; ++h) {
            f4 lx = LX4[g+h], ly = LY4[g+h], lz = LZ4[g+h], sl = SL4[g+h];
            f4 tA = shifted_d2(lx, ly, lz, sl, xA0, xA1, xA2);
            f4 tB = shifted_d2(lx, ly, lz, sl, xB0, xB1, xB2);
            f4 pA, pB;
            #pragma unroll
            for (int e = 0; e < 4; ++e) {
                float ivA = __builtin_amdgcn_rsqf(fmaxf(tA[e] + AA, 1e-12f));
                float ivB = __builtin_amdgcn_rsqf(fmaxf(tB[e] + AB, 1e-12f));
                pA[e] = __builtin_amdgcn_exp2f(fmaf(ivA, L2E, nmA));
                pB[e] = __builtin_amdgcn_exp2f(fmaf(ivB, L2E, nmB));
            }
            afA.u[2*h]   = packbf2(pA[0], pA[1]);
            afA.u[2*h+1] = packbf2(pA[2], pA[3]);
            afB.u[2*h]   = packbf2(pB[0], pB[1]);
            afB.u[2*h+1] = packbf2(pB[2], pB[3]);
        }
        acc2A[0] = __builtin_amdgcn_mfma_f32_16x16x32_bf16(afA.v, bf0, acc2A[0], 0, 0, 0);
        acc2B[0] = __builtin_amdgcn_mfma_f32_16x16x32_bf16(afB.v, bf0, acc2B[0], 0, 0, 0);
        acc2A[1] = __builtin_amdgcn_mfma_f32_16x16x32_bf16(afA.v, bf1, acc2A[1], 0, 0, 0);
        acc2B[1] = __builtin_amdgcn_mfma_f32_16x16x32_bf16(afB.v, bf1, acc2B[1], 0, 0, 0);
        acc2A[2] = __builtin_amdgcn_mfma_f32_16x16x32_bf16(afA.v, bf2, acc2A[2], 0, 0, 0);
        acc2B[2] = __builtin_amdgcn_mfma_f32_16x16x32_bf16(afB.v, bf2, acc2B[2], 0, 0, 0);
        acc2A[3] = __builtin_amdgcn_mfma_f32_16x16x32_bf16(afA.v, bf3, acc2A[3], 0, 0, 0);
        acc2B[3] = __builtin_amdgcn_mfma_f32_16x16x32_bf16(afB.v, bf3, acc2B[3], 0, 0, 0);
        accLA = __builtin_amdgcn_mfma_f32_16x16x32_bf16(afA.v, ONES, accLA, 0, 0, 0);
        accLB = __builtin_amdgcn_mfma_f32_16x16x32_bf16(afB.v, ONES, accLB, 0, 0, 0);
    }
    {   // ---------- peeled chunk 31: features 992..1023, only quad 0 is real ----------
        // nm = -inf on pad lanes: t+A ~ 3e18 -> rsq tiny -> fma(tiny,L2E,-inf) = -inf
        // -> exp2 = exactly 0, so pads contribute nothing to feats or ls.
        const int c = NCHUNK-1;
        const short8* bp = (const short8*)fvB + (c*4 + quad)*64;
        short8 bf0 = bp[ptl];
        short8 bf1 = bp[16 + ptl];
        short8 bf2 = bp[32 + ptl];
        short8 bf3 = bp[48 + ptl];

        const int g = c*8 + quad*2;
        const float nmAe = (quad != 0) ? -__builtin_inff() : nmA;
        const float nmBe = (quad != 0) ? -__builtin_inff() : nmB;
        union { short8 v; unsigned int u[4]; } afA, afB;
        #pragma unroll
        for (int h = 0; h < 2; ++h) {
            f4 lx = LX4[g+h], ly = LY4[g+h], lz = LZ4[g+h], sl = SL4[g+h];
            f4 tA = shifted_d2(lx, ly, lz, sl, xA0, xA1, xA2);
            f4 tB = shifted_d2(lx, ly, lz, sl, xB0, xB1, xB2);
            f4 pA, pB;
            #pragma unroll
            for (int e = 0; e < 4; ++e) {
                float ivA = __builtin_amdgcn_rsqf(fmaxf(tA[e] + AA, 1e-12f));
                float ivB = __builtin_amdgcn_rsqf(fmaxf(tB[e] + AB, 1e-12f));
                pA[e] = __builtin_amdgcn_exp2f(fmaf(ivA, L2E, nmAe));
                pB[e] = __builtin_amdgcn_exp2f(fmaf(ivB, L2E, nmBe));
            }
            afA.u[2*h]   = packbf2(pA[0], pA[1]);
            afA.u[2*h+1] = packbf2(pA[2], pA[3]);
            afB.u[2*h]   = packbf2(pB[0], pB[1]);
            afB.u[2*h+1] = packbf2(pB[2], pB[3]);
        }
        acc2A[0] = __builtin_amdgcn_mfma_f32_16x16x32_bf16(afA.v, bf0, acc2A[0], 0, 0, 0);
        acc2B[0] = __builtin_amdgcn_mfma_f32_16x16x32_bf16(afB.v, bf0, acc2B[0], 0, 0, 0);
        acc2A[1] = __builtin_amdgcn_mfma_f32_16x16x32_bf16(afA.v, bf1, acc2A[1], 0, 0, 0);
        acc2B[1] = __builtin_amdgcn_mfma_f32_16x16x32_bf16(afB.v, bf1, acc2B[1], 0, 0, 0);
        acc2A[2] = __builtin_amdgcn_mfma_f32_16x16x32_bf16(afA.v, bf2, acc2A[2], 0, 0, 0);
        acc2B[2] = __builtin_amdgcn_mfma_f32_16x16x32_bf16(afB.v, bf2, acc2B[2], 0, 0, 0);
        acc2A[3] = __builtin_amdgcn_mfma_f32_16x16x32_bf16(afA.v, bf3, acc2A[3], 0, 0, 0);
        acc2B[3] = __builtin_amdgcn_mfma_f32_16x16x32_bf16(afB.v, bf3, acc2B[3], 0, 0, 0);
        accLA = __builtin_amdgcn_mfma_f32_16x16x32_bf16(afA.v, ONES, accLA, 0, 0, 0);
        accLB = __builtin_amdgcn_mfma_f32_16x16x32_bf16(afB.v, ONES, accLB, 0, 0, 0);
    }

    float linvA[4], linvB[4];
    #pragma unroll
    for (int r = 0; r < 4; ++r) {
        linvA[r] = __builtin_amdgcn_rcpf(accLA[r]);
        linvB[r] = __builtin_amdgcn_rcpf(accLB[r]);
    }

    // ---------- stage y = [PE(36) | feats(64) | zero pad to 128] for both tiles ----
    const int myrowA = (wv*32 + ptl) * 136;
    const int myrowB = (wv*32 + 16 + ptl) * 136;
    *(short8*)&act[myrowA + 96 + quad*8] = (short8)0;
    *(short8*)&act[myrowB + 96 + quad*8] = (short8)0;

    #pragma unroll
    for (int i = 0; i < 9; ++i) {
        int k = quad*9 + i;
        int d = k / 12, r12 = k % 12, l = r12 % 6;
        float fr = PI_F * (float)(1 << l);
        float xvA = (d == 0) ? xA0 : (d == 1) ? xA1 : xA2;
        float xvB = (d == 0) ? xB0 : (d == 1) ? xB1 : xB2;
        float vA = (r12 < 6) ? __sinf(xvA * fr) : __cosf(xvA * fr);
        float vB = (r12 < 6) ? __sinf(xvB * fr) : __cosf(xvB * fr);
        act[myrowA + k] = f2bf(vA);
        act[myrowB + k] = f2bf(vB);
    }

    #pragma unroll
    for (int nt = 0; nt < 4; ++nt)
        #pragma unroll
        for (int r = 0; r < 4; ++r) {
            act[(wv*32 + quad*4 + r)*136 + 36 + nt*16 + ptl]      = f2bf(acc2A[nt][r] * linvA[r]);
            act[(wv*32 + 16 + quad*4 + r)*136 + 36 + nt*16 + ptl] = f2bf(acc2B[nt][r] * linvB[r]);
        }

    // ---------- MLP layers 0..3 via MFMA, weights direct from L2 (no barriers) ----
    short8 aA[4], aB[4];
    #pragma unroll 1
    for (int t = 0; t < 16; ++t) {
        const int L = t >> 2, q = t & 3;
        if (q == 0) {      // new layer: capture input activations (wave-private rows)
            #pragma unroll
            for (int c = 0; c < 4; ++c) {
                aA[c] = *(const short8*)&act[myrowA + c*32 + quad*8];
                aB[c] = *(const short8*)&act[myrowB + c*32 + quad*8];
            }
        }
        const float* bL = (L == 0) ? b0 : (L == 1) ? b1 : (L == 2) ? b2 : b3;
        const short8* bp = (const short8*)WB + t*512;   // 8KB quarter-layer stage
        #pragma unroll
        for (int nt = 0; nt < 2; ++nt) {
            floatx4 accA = {}, accB = {};
            #pragma unroll
            for (int c = 0; c < 4; ++c) {
                short8 bw = bp[(nt*4 + c)*64 + lane];
                accA = __builtin_amdgcn_mfma_f32_16x16x32_bf16(aA[c], bw, accA, 0, 0, 0);
                accB = __builtin_amdgcn_mfma_f32_16x16x32_bf16(aB[c], bw, accB, 0, 0, 0);
            }
            const int col = (q*2 + nt)*16 + ptl;
            const float bias = bL[col];
            #pragma unroll
            for (int r = 0; r < 4; ++r) {
                float hA = accA[r] + bias;
                float hB = accB[r] + bias;
                float sA = __sinf(hA);
                float sB = __sinf(hB);
                hA = 0.5f*hA + sA*sA;                   // SnakeAlt
                hB = 0.5f*hB + sB*sB;
                act[(wv*32 + quad*4 + r)*136 + col]      = f2bf(hA);
                act[(wv*32 + 16 + quad*4 + r)*136 + col] = f2bf(hB);
            }
        }
    }

    // ---------- layer 4: 128 -> 1 (W4 loads shared across both tiles) ----------
    float oA = 0.f, oB = 0.f;
    #pragma unroll
    for (int s = 0; s < 4; ++s) {
        short8 avA = *(const short8*)&act[myrowA + quad*32 + s*8];
        short8 avB = *(const short8*)&act[myrowB + quad*32 + s*8];
        const floatx4* wp = (const floatx4*)W4 + (quad*32 + s*8)/4;
        floatx4 w0 = wp[0], w1 = wp[1];
        oA = fmaf(bf2f((unsigned short)avA[0]), w0[0], oA);
        oB = fmaf(bf2f((unsigned short)avB[0]), w0[0], oB);
        oA = fmaf(bf2f((unsigned short)avA[1]), w0[1], oA);
        oB = fmaf(bf2f((unsigned short)avB[1]), w0[1], oB);
        oA = fmaf(bf2f((unsigned short)avA[2]), w0[2], oA);
        oB = fmaf(bf2f((unsigned short)avB[2]), w0[2], oB);
        oA = fmaf(bf2f((unsigned short)avA[3]), w0[3], oA);
        oB = fmaf(bf2f((unsigned short)avB[3]), w0[3], oB);
        oA = fmaf(bf2f((unsigned short)avA[4]), w1[0], oA);
        oB = fmaf(bf2f((unsigned short)avB[4]), w1[0], oB);
        oA = fmaf(bf2f((unsigned short)avA[5]), w1[1], oA);
        oB = fmaf(bf2f((unsigned short)avB[5]), w1[1], oB);
        oA = fmaf(bf2f((unsigned short)avA[6]), w1[2], oA);
        oB = fmaf(bf2f((unsigned short)avB[6]), w1[2], oB);
        oA = fmaf(bf2f((unsigned short)avA[7]), w1[3], oA);
        oB = fmaf(bf2f((unsigned short)avB[7]), w1[3], oB);
    }
    oA += __shfl_xor(oA, 16);
    oA += __shfl_xor(oA, 32);
    oB += __shfl_xor(oB, 16);
    oB += __shfl_xor(oB, 32);
    if (quad == 0) {
        float bb = b4[0];
        out[ptbase + ptl]      = oA + bb;
        out[ptbase + 16 + ptl] = oB + bb;
    }
}

extern "C" void kernel_launch(void* const* d_in, const int* in_sizes, int n_in,
                              void* d_out, int out_size, void* d_ws, size_t ws_size,
                              hipStream_t stream)
{
    const float* x  = (const float*)d_in[0];
    const float* lc = (const float*)d_in[1];
    const float* fv = (const float*)d_in[2];
    const float* W0 = (const float*)d_in[3];
    const float* b0 = (const float*)d_in[4];
    const float* W1 = (const float*)d_in[5];
    const float* b1 = (const float*)d_in[6];
    const float* W2 = (const float*)d_in[7];
    const float* b2 = (const float*)d_in[8];
    const float* W3 = (const float*)d_in[9];
    const float* b3 = (const float*)d_in[10];
    const float* W4 = (const float*)d_in[11];
    const float* b4 = (const float*)d_in[12];

    char* ws = (char*)d_ws;
    float*          LXp = (float*)(ws + 0);
    float*          LYp = (float*)(ws + 4096);
    float*          LZp = (float*)(ws + 8192);
    float*          SLp = (float*)(ws + 12288);
    unsigned short* fvB = (unsigned short*)(ws + 16384);            // 128 KB
    unsigned short* WB  = (unsigned short*)(ws + 16384 + 131072);   // 128 KB

    prep_all<<<dim3(516), dim3(256), 0, stream>>>(lc, fv, W0, W1, W2, W3,
                                                  LXp, LYp, LZp, SLp, fvB, WB);

    afvsrn_mfma<<<dim3(N_PTS/128), dim3(256), 0, stream>>>(
        x, LXp, LYp, LZp, SLp, fvB, WB, b0, b1, b2, b3, W4, b4, (float*)d_out);
}

// Round 9
// 157.869 us; speedup vs baseline: 1.2797x; 1.2241x over previous
//
#include <hip/hip_runtime.h>
#include <hip/hip_bf16.h>

#define N_PTS   131072
#define N_FEATS 1000
#define FDIM    64
#define HID     128
#define NCHUNK  32          // 32 K-chunks of 32 features (padded 1000 -> 1024)
#define PI_F    3.14159265358979f
#define L2E     1.44269504f

typedef short  short8  __attribute__((ext_vector_type(8)));   // bf16 A/B frag (4 VGPRs)
typedef float  floatx4 __attribute__((ext_vector_type(4)));   // C/D frag

// ---- bf16 helpers ----
__device__ __forceinline__ unsigned int packbf2(float a, float b) {
    float2 t; t.x = a; t.y = b;
    __hip_bfloat162 h = __float22bfloat162_rn(t);
    union { __hip_bfloat162 hh; unsigned int u; } cv; cv.hh = h;
    return cv.u;
}
__device__ __forceinline__ unsigned short f2bf(float f) {      // RNE, 1 v_cvt_pk
    return (unsigned short)packbf2(f, f);
}
__device__ __forceinline__ float bf2f(unsigned short h) {
    return __uint_as_float(((unsigned int)h) << 16);
}
__device__ __forceinline__ floatx4 min3_4(floatx4 a, floatx4 b, floatx4 c) {
    floatx4 r;
    r[0] = fminf(fminf(a[0], b[0]), c[0]);
    r[1] = fminf(fminf(a[1], b[1]), c[1]);
    r[2] = fminf(fminf(a[2], b[2]), c[2]);
    r[3] = fminf(fminf(a[3], b[3]), c[3]);
    return r;
}

// ============================================================================
// d2 VIA MFMA. d2[f][p] = |loc_f|^2 - 2 loc_f . x_p + |x_p|^2 is a K-slot dot:
// triple bf16 split (hi/mid/lo, 24-bit effective) of both sides, 24 K-slots:
//   per dim d (slots d*6+t): A(loc)=[lh,lh,lm,lh,lm,ll], B(x)=[xh,xm,xh,xl,xm,xh]
//     -> lh*xh + lh*xm + lm*xh + lh*xl + lm*xm + ll*xh ~= (-2loc_d)*x_d  (err ~2^-24)
//   slots 18..20: A=[SLh,SLm,SLl], B=1   (|loc|^2)
//   slots 21..23: A=1,            B=[Ah,Am,Al]  (|x|^2)
//   slots 24..31: 0
// bf16*bf16 products are exact in fp32; total d2 error ~1e-7 (fp32-class).
// Pass 1 and pass 2 issue the IDENTICAL mfma -> d2 bit-identical across passes.
// C-frag layout: col=lane&15=point, row=quad*4+r=feature.
// ============================================================================

// x-side (B operand) fragment: lane quad selects its 8 K-slots for its point.
__device__ __forceinline__ short8 xfrag_build(int quad, float x0, float x1, float x2) {
    unsigned short h0, m0, l0, h1, m1, l1, h2, m2, l2, Ah, Am, Al;
    { h0 = f2bf(x0); float r = x0 - bf2f(h0); m0 = f2bf(r); l0 = f2bf(r - bf2f(m0)); }
    { h1 = f2bf(x1); float r = x1 - bf2f(h1); m1 = f2bf(r); l1 = f2bf(r - bf2f(m1)); }
    { h2 = f2bf(x2); float r = x2 - bf2f(h2); m2 = f2bf(r); l2 = f2bf(r - bf2f(m2)); }
    float A = x0*x0 + x1*x1 + x2*x2;
    { Ah = f2bf(A); float r = A - bf2f(Ah); Am = f2bf(r); Al = f2bf(r - bf2f(Am)); }
    union { short8 v; unsigned short u[8]; } f;
    if (quad == 0) {        // slots 0..7: d0 t0..5, d1 t0..1
        f.u[0]=h0; f.u[1]=m0; f.u[2]=h0; f.u[3]=l0; f.u[4]=m0; f.u[5]=h0; f.u[6]=h1; f.u[7]=m1;
    } else if (quad == 1) { // slots 8..15: d1 t2..5, d2 t0..3
        f.u[0]=h1; f.u[1]=l1; f.u[2]=m1; f.u[3]=h1; f.u[4]=h2; f.u[5]=m2; f.u[6]=h2; f.u[7]=l2;
    } else if (quad == 2) { // slots 16..23: d2 t4..5, SL-pair ones, |x|^2 split
        f.u[0]=m2; f.u[1]=h2; f.u[2]=0x3F80; f.u[3]=0x3F80; f.u[4]=0x3F80; f.u[5]=Ah; f.u[6]=Am; f.u[7]=Al;
    } else {
        f.v = (short8)0;    // slots 24..31 all zero
    }
    return f.v;
}

// ---------------- fused prep ----------------
// fvB: k-slot remap to match MFMA-computed p layout:
//   i = ((c*4+quad)*64 + n)*8 + j ; f = c*32 + ((j<4)? quad*4+j : 16+quad*4+(j-4))
//   value = fv[f][n]  (0 for f >= N_FEATS)
// WB: 16 stages (4 layers x 4 quarters) of 8KB, lane-indexed (unchanged):
//   r = ((((L*4+q)*2 + nt)*4 + c)*64 + lane)*8 + j
// DB: loc-side A-frags for the d2 MFMA. 64 fragsets (16 features each):
//   r = ((fg*4 + quad)*16 + ft)*8 + j ; feature f = fg*16+ft ; slot s = quad*8+j
//   pads (f >= N_FEATS) use loc = 1e9 -> d2 ~ 3e18, never the min.
__global__ void prep_all(const float* __restrict__ locs, const float* __restrict__ fv,
                         const float* __restrict__ W0, const float* __restrict__ W1,
                         const float* __restrict__ W2, const float* __restrict__ W3,
                         unsigned short* __restrict__ DB,
                         unsigned short* __restrict__ fvB, unsigned short* __restrict__ WB)
{
    int i = blockIdx.x * 256 + threadIdx.x;
    if (i < 65536) {
        int j = i & 7, n = (i >> 3) & 63, cq = i >> 9;
        int c = cq >> 2, quad = cq & 3;
        int fl = (j < 4) ? quad*4 + j : 16 + quad*4 + (j - 4);
        int f = c*32 + fl;
        float v = (f < N_FEATS) ? fv[f*FDIM + n] : 0.f;
        fvB[i] = f2bf(v);
    } else if (i < 131072) {
        int r = i - 65536;
        int j = r & 7, lane = (r >> 3) & 63, c = (r >> 9) & 3;
        int nt = (r >> 11) & 1, q = (r >> 12) & 3, L = r >> 14;
        int n = (q*2 + nt)*16 + (lane & 15);
        int k = c*32 + (lane >> 4)*8 + j;
        const float* W = (L == 0) ? W0 : (L == 1) ? W1 : (L == 2) ? W2 : W3;
        int Kin = (L == 0) ? 100 : 128;
        float v = (k < Kin) ? W[n*Kin + k] : 0.f;
        WB[r] = f2bf(v);
    } else if (i < 163840) {
        int r = i - 131072;
        int j = r & 7, ft = (r >> 3) & 15, quad = (r >> 7) & 3, fg = r >> 9;
        int f = fg*16 + ft, s = quad*8 + j;
        float lx, ly, lz;
        if (f < N_FEATS) { lx = locs[f*3+0]; ly = locs[f*3+1]; lz = locs[f*3+2]; }
        else             { lx = 1e9f; ly = 1e9f; lz = 1e9f; }
        unsigned short val = 0;
        if (s < 18) {
            int d = s / 6, t = s - d*6;
            float l2 = -2.f * ((d == 0) ? lx : (d == 1) ? ly : lz);
            unsigned short h = f2bf(l2);
            float r1 = l2 - bf2f(h);
            unsigned short m = f2bf(r1);
            unsigned short l = f2bf(r1 - bf2f(m));
            val = (t == 2 || t == 4) ? m : (t == 5) ? l : h;
        } else if (s < 21) {
            float SL = lx*lx + ly*ly + lz*lz;
            unsigned short h = f2bf(SL);
            float r1 = SL - bf2f(h);
            unsigned short m = f2bf(r1);
            unsigned short l = f2bf(r1 - bf2f(m));
            val = (s == 18) ? h : (s == 19) ? m : l;
        } else if (s < 24) {
            val = 0x3F80;   // 1.0 (pairs with B-side |x|^2 split)
        }
        DB[r] = val;
    }
}

// ---------------- main fused kernel ----------------
// 4 waves/block, 32 points/wave (two 16-pt tiles), zero __syncthreads,
// all operands direct from L2-resident workspace.
// d2 computed by MFMA in BOTH passes (identical instr -> bit-identical),
// killing the scalar dot products (-48 VALU/chunk) and the +|x|^2 adds.
// launch_bounds(256,3): R5/R7 proved (256,4) spills; 3 waves/SIMD is the
// occupancy; this round cuts issue count structurally instead.
__global__ __launch_bounds__(256, 3)
void afvsrn_mfma(const float* __restrict__ x,
                 const unsigned short* __restrict__ DB,
                 const unsigned short* __restrict__ fvB,
                 const unsigned short* __restrict__ WB,
                 const float* __restrict__ b0, const float* __restrict__ b1,
                 const float* __restrict__ b2, const float* __restrict__ b3,
                 const float* __restrict__ W4, const float* __restrict__ b4,
                 float* __restrict__ out)
{
    __shared__ unsigned short act[128 * 136];                 // [128 pts][128+8 pad] bf16

    const int lane = threadIdx.x & 63;
    const int wv   = threadIdx.x >> 6;
    const int ptl  = lane & 15;
    const int quad = lane >> 4;
    const int ptbase = blockIdx.x * 128 + wv * 32;

    const float xA0 = x[(ptbase + ptl)*3 + 0];
    const float xA1 = x[(ptbase + ptl)*3 + 1];
    const float xA2 = x[(ptbase + ptl)*3 + 2];
    const float xB0 = x[(ptbase + 16 + ptl)*3 + 0];
    const float xB1 = x[(ptbase + 16 + ptl)*3 + 1];
    const float xB2 = x[(ptbase + 16 + ptl)*3 + 2];

    // x-side B fragments for the d2 MFMA (held across both passes)
    const short8 xfA = xfrag_build(quad, xA0, xA1, xA2);
    const short8 xfB = xfrag_build(quad, xB0, xB1, xB2);

    const short8* DBp = (const short8*)DB;
    const int dbidx = quad*16 + ptl;           // A-frag lane slot within a fragset
    const floatx4 Z = {0.f, 0.f, 0.f, 0.f};

    // ---------- pass 1: min d2 via MFMA (lane holds 4 features x its point) ----------
    floatx4 mnA = {1e30f, 1e30f, 1e30f, 1e30f};
    floatx4 mnB = {1e30f, 1e30f, 1e30f, 1e30f};
    #pragma unroll 2
    for (int c = 0; c < NCHUNK; ++c) {
        short8 a0 = DBp[(2*c    )*64 + dbidx];
        short8 a1 = DBp[(2*c + 1)*64 + dbidx];
        floatx4 dA0 = __builtin_amdgcn_mfma_f32_16x16x32_bf16(a0, xfA, Z, 0, 0, 0);
        floatx4 dA1 = __builtin_amdgcn_mfma_f32_16x16x32_bf16(a1, xfA, Z, 0, 0, 0);
        floatx4 dB0 = __builtin_amdgcn_mfma_f32_16x16x32_bf16(a0, xfB, Z, 0, 0, 0);
        floatx4 dB1 = __builtin_amdgcn_mfma_f32_16x16x32_bf16(a1, xfB, Z, 0, 0, 0);
        mnA = min3_4(mnA, dA0, dA1);
        mnB = min3_4(mnB, dB0, dB1);
    }
    float mdA = fminf(fminf(mnA[0], mnA[1]), fminf(mnA[2], mnA[3]));
    float mdB = fminf(fminf(mnB[0], mnB[1]), fminf(mnB[2], mnB[3]));
    mdA = fminf(mdA, __shfl_xor(mdA, 16));
    mdA = fminf(mdA, __shfl_xor(mdA, 32));
    mdB = fminf(mdB, __shfl_xor(mdB, 16));
    mdB = fminf(mdB, __shfl_xor(mdB, 32));
    // m = max inv_d = rsqrt(min d2); pass 2 recomputes the SAME MFMA -> the
    // argmin element's d2 is bit-identical -> p_argmin = exp2(~0) ~ 1, no overflow.
    const float nmA = -__builtin_amdgcn_rsqf(fmaxf(mdA, 1e-12f)) * L2E;
    const float nmB = -__builtin_amdgcn_rsqf(fmaxf(mdB, 1e-12f)) * L2E;

    // ---------- pass 2: p = exp2(fma(rsq(d2), log2e, nm)); GEMM feats = p @ fv ----
    // p lands in C-frag layout (features quad*4+r per half) which maps straight
    // into the GEMM A-frag k-slots via the fvB remap (j<4: D0, j>=4: D1).
    // ls comes free from an extra MFMA vs all-ones B; its C row = the point
    // whose linv each lane needs -> no shuffles. Chunk 31 (pads) peeled.
    const short8 ONES = {0x3F80,0x3F80,0x3F80,0x3F80,0x3F80,0x3F80,0x3F80,0x3F80};
    floatx4 acc2A[4] = {}, acc2B[4] = {};
    floatx4 accLA = {}, accLB = {};
    #pragma unroll 1
    for (int c = 0; c < NCHUNK-1; ++c) {
        const short8* bp = (const short8*)fvB + (c*4 + quad)*64;
        short8 bf0 = bp[ptl];
        short8 bf1 = bp[16 + ptl];
        short8 bf2 = bp[32 + ptl];
        short8 bf3 = bp[48 + ptl];

        short8 a0 = DBp[(2*c    )*64 + dbidx];
        short8 a1 = DBp[(2*c + 1)*64 + dbidx];
        floatx4 dA0 = __builtin_amdgcn_mfma_f32_16x16x32_bf16(a0, xfA, Z, 0, 0, 0);
        floatx4 dA1 = __builtin_amdgcn_mfma_f32_16x16x32_bf16(a1, xfA, Z, 0, 0, 0);
        floatx4 dB0 = __builtin_amdgcn_mfma_f32_16x16x32_bf16(a0, xfB, Z, 0, 0, 0);
        floatx4 dB1 = __builtin_amdgcn_mfma_f32_16x16x32_bf16(a1, xfB, Z, 0, 0, 0);

        union { short8 v; unsigned int u[4]; } afA, afB;
        {
            float p0, p1;
            p0 = __builtin_amdgcn_exp2f(fmaf(__builtin_amdgcn_rsqf(fmaxf(dA0[0], 1e-12f)), L2E, nmA));
            p1 = __builtin_amdgcn_exp2f(fmaf(__builtin_amdgcn_rsqf(fmaxf(dA0[1], 1e-12f)), L2E, nmA));
            afA.u[0] = packbf2(p0, p1);
            p0 = __builtin_amdgcn_exp2f(fmaf(__builtin_amdgcn_rsqf(fmaxf(dA0[2], 1e-12f)), L2E, nmA));
            p1 = __builtin_amdgcn_exp2f(fmaf(__builtin_amdgcn_rsqf(fmaxf(dA0[3], 1e-12f)), L2E, nmA));
            afA.u[1] = packbf2(p0, p1);
            p0 = __builtin_amdgcn_exp2f(fmaf(__builtin_amdgcn_rsqf(fmaxf(dA1[0], 1e-12f)), L2E, nmA));
            p1 = __builtin_amdgcn_exp2f(fmaf(__builtin_amdgcn_rsqf(fmaxf(dA1[1], 1e-12f)), L2E, nmA));
            afA.u[2] = packbf2(p0, p1);
            p0 = __builtin_amdgcn_exp2f(fmaf(__builtin_amdgcn_rsqf(fmaxf(dA1[2], 1e-12f)), L2E, nmA));
            p1 = __builtin_amdgcn_exp2f(fmaf(__builtin_amdgcn_rsqf(fmaxf(dA1[3], 1e-12f)), L2E, nmA));
            afA.u[3] = packbf2(p0, p1);
            p0 = __builtin_amdgcn_exp2f(fmaf(__builtin_amdgcn_rsqf(fmaxf(dB0[0], 1e-12f)), L2E, nmB));
            p1 = __builtin_amdgcn_exp2f(fmaf(__builtin_amdgcn_rsqf(fmaxf(dB0[1], 1e-12f)), L2E, nmB));
            afB.u[0] = packbf2(p0, p1);
            p0 = __builtin_amdgcn_exp2f(fmaf(__builtin_amdgcn_rsqf(fmaxf(dB0[2], 1e-12f)), L2E, nmB));
            p1 = __builtin_amdgcn_exp2f(fmaf(__builtin_amdgcn_rsqf(fmaxf(dB0[3], 1e-12f)), L2E, nmB));
            afB.u[1] = packbf2(p0, p1);
            p0 = __builtin_amdgcn_exp2f(fmaf(__builtin_amdgcn_rsqf(fmaxf(dB1[0], 1e-12f)), L2E, nmB));
            p1 = __builtin_amdgcn_exp2f(fmaf(__builtin_amdgcn_rsqf(fmaxf(dB1[1], 1e-12f)), L2E, nmB));
            afB.u[2] = packbf2(p0, p1);
            p0 = __builtin_amdgcn_exp2f(fmaf(__builtin_amdgcn_rsqf(fmaxf(dB1[2], 1e-12f)), L2E, nmB));
            p1 = __builtin_amdgcn_exp2f(fmaf(__builtin_amdgcn_rsqf(fmaxf(dB1[3], 1e-12f)), L2E, nmB));
            afB.u[3] = packbf2(p0, p1);
        }
        acc2A[0] = __builtin_amdgcn_mfma_f32_16x16x32_bf16(afA.v, bf0, acc2A[0], 0, 0, 0);
        acc2B[0] = __builtin_amdgcn_mfma_f32_16x16x32_bf16(afB.v, bf0, acc2B[0], 0, 0, 0);
        acc2A[1] = __builtin_amdgcn_mfma_f32_16x16x32_bf16(afA.v, bf1, acc2A[1], 0, 0, 0);
        acc2B[1] = __builtin_amdgcn_mfma_f32_16x16x32_bf16(afB.v, bf1, acc2B[1], 0, 0, 0);
        acc2A[2] = __builtin_amdgcn_mfma_f32_16x16x32_bf16(afA.v, bf2, acc2A[2], 0, 0, 0);
        acc2B[2] = __builtin_amdgcn_mfma_f32_16x16x32_bf16(afB.v, bf2, acc2B[2], 0, 0, 0);
        acc2A[3] = __builtin_amdgcn_mfma_f32_16x16x32_bf16(afA.v, bf3, acc2A[3], 0, 0, 0);
        acc2B[3] = __builtin_amdgcn_mfma_f32_16x16x32_bf16(afB.v, bf3, acc2B[3], 0, 0, 0);
        accLA = __builtin_amdgcn_mfma_f32_16x16x32_bf16(afA.v, ONES, accLA, 0, 0, 0);
        accLB = __builtin_amdgcn_mfma_f32_16x16x32_bf16(afB.v, ONES, accLB, 0, 0, 0);
    }
    {   // ---------- peeled chunk 31: features 992..1023 ----------
        // D0 half (992..1007): quads 0,1 real (992..999), quads 2,3 pad.
        // D1 half (1008..1023): all pad -> p = 0 (af slots 4..7 zeroed).
        const int c = NCHUNK-1;
        const short8* bp = (const short8*)fvB + (c*4 + quad)*64;
        short8 bf0 = bp[ptl];
        short8 bf1 = bp[16 + ptl];
        short8 bf2 = bp[32 + ptl];
        short8 bf3 = bp[48 + ptl];

        short8 a0 = DBp[(2*c)*64 + dbidx];
        floatx4 dA0 = __builtin_amdgcn_mfma_f32_16x16x32_bf16(a0, xfA, Z, 0, 0, 0);
        floatx4 dB0 = __builtin_amdgcn_mfma_f32_16x16x32_bf16(a0, xfB, Z, 0, 0, 0);
        const float nmAe = (quad < 2) ? nmA : -__builtin_inff();
        const float nmBe = (quad < 2) ? nmB : -__builtin_inff();
        union { short8 v; unsigned int u[4]; } afA, afB;
        {
            float p0, p1;
            p0 = __builtin_amdgcn_exp2f(fmaf(__builtin_amdgcn_rsqf(fmaxf(dA0[0], 1e-12f)), L2E, nmAe));
            p1 = __builtin_amdgcn_exp2f(fmaf(__builtin_amdgcn_rsqf(fmaxf(dA0[1], 1e-12f)), L2E, nmAe));
            afA.u[0] = packbf2(p0, p1);
            p0 = __builtin_amdgcn_exp2f(fmaf(__builtin_amdgcn_rsqf(fmaxf(dA0[2], 1e-12f)), L2E, nmAe));
            p1 = __builtin_amdgcn_exp2f(fmaf(__builtin_amdgcn_rsqf(fmaxf(dA0[3], 1e-12f)), L2E, nmAe));
            afA.u[1] = packbf2(p0, p1);
            afA.u[2] = 0; afA.u[3] = 0;
            p0 = __builtin_amdgcn_exp2f(fmaf(__builtin_amdgcn_rsqf(fmaxf(dB0[0], 1e-12f)), L2E, nmBe));
            p1 = __builtin_amdgcn_exp2f(fmaf(__builtin_amdgcn_rsqf(fmaxf(dB0[1], 1e-12f)), L2E, nmBe));
            afB.u[0] = packbf2(p0, p1);
            p0 = __builtin_amdgcn_exp2f(fmaf(__builtin_amdgcn_rsqf(fmaxf(dB0[2], 1e-12f)), L2E, nmBe));
            p1 = __builtin_amdgcn_exp2f(fmaf(__builtin_amdgcn_rsqf(fmaxf(dB0[3], 1e-12f)), L2E, nmBe));
            afB.u[1] = packbf2(p0, p1);
            afB.u[2] = 0; afB.u[3] = 0;
        }
        acc2A[0] = __builtin_amdgcn_mfma_f32_16x16x32_bf16(afA.v, bf0, acc2A[0], 0, 0, 0);
        acc2B[0] = __builtin_amdgcn_mfma_f32_16x16x32_bf16(afB.v, bf0, acc2B[0], 0, 0, 0);
        acc2A[1] = __builtin_amdgcn_mfma_f32_16x16x32_bf16(afA.v, bf1, acc2A[1], 0, 0, 0);
        acc2B[1] = __builtin_amdgcn_mfma_f32_16x16x32_bf16(afB.v, bf1, acc2B[1], 0, 0, 0);
        acc2A[2] = __builtin_amdgcn_mfma_f32_16x16x32_bf16(afA.v, bf2, acc2A[2], 0, 0, 0);
        acc2B[2] = __builtin_amdgcn_mfma_f32_16x16x32_bf16(afB.v, bf2, acc2B[2], 0, 0, 0);
        acc2A[3] = __builtin_amdgcn_mfma_f32_16x16x32_bf16(afA.v, bf3, acc2A[3], 0, 0, 0);
        acc2B[3] = __builtin_amdgcn_mfma_f32_16x16x32_bf16(afB.v, bf3, acc2B[3], 0, 0, 0);
        accLA = __builtin_amdgcn_mfma_f32_16x16x32_bf16(afA.v, ONES, accLA, 0, 0, 0);
        accLB = __builtin_amdgcn_mfma_f32_16x16x32_bf16(afB.v, ONES, accLB, 0, 0, 0);
    }

    float linvA[4], linvB[4];
    #pragma unroll
    for (int r = 0; r < 4; ++r) {
        linvA[r] = __builtin_amdgcn_rcpf(accLA[r]);
        linvB[r] = __builtin_amdgcn_rcpf(accLB[r]);
    }

    // ---------- stage y = [PE(36) | feats(64) | zero pad to 128] for both tiles ----
    const int myrowA = (wv*32 + ptl) * 136;
    const int myrowB = (wv*32 + 16 + ptl) * 136;
    *(short8*)&act[myrowA + 96 + quad*8] = (short8)0;
    *(short8*)&act[myrowB + 96 + quad*8] = (short8)0;

    #pragma unroll
    for (int i = 0; i < 9; ++i) {
        int k = quad*9 + i;
        int d = k / 12, r12 = k % 12, l = r12 % 6;
        float fr = PI_F * (float)(1 << l);
        float xvA = (d == 0) ? xA0 : (d == 1) ? xA1 : xA2;
        float xvB = (d == 0) ? xB0 : (d == 1) ? xB1 : xB2;
        float vA = (r12 < 6) ? __sinf(xvA * fr) : __cosf(xvA * fr);
        float vB = (r12 < 6) ? __sinf(xvB * fr) : __cosf(xvB * fr);
        act[myrowA + k] = f2bf(vA);
        act[myrowB + k] = f2bf(vB);
    }

    #pragma unroll
    for (int nt = 0; nt < 4; ++nt)
        #pragma unroll
        for (int r = 0; r < 4; ++r) {
            act[(wv*32 + quad*4 + r)*136 + 36 + nt*16 + ptl]      = f2bf(acc2A[nt][r] * linvA[r]);
            act[(wv*32 + 16 + quad*4 + r)*136 + 36 + nt*16 + ptl] = f2bf(acc2B[nt][r] * linvB[r]);
        }

    // ---------- MLP layers 0..3 via MFMA, weights direct from L2 (no barriers) ----
    short8 aA[4], aB[4];
    #pragma unroll 1
    for (int t = 0; t < 16; ++t) {
        const int L = t >> 2, q = t & 3;
        if (q == 0) {      // new layer: capture input activations (wave-private rows)
            #pragma unroll
            for (int c = 0; c < 4; ++c) {
                aA[c] = *(const short8*)&act[myrowA + c*32 + quad*8];
                aB[c] = *(const short8*)&act[myrowB + c*32 + quad*8];
            }
        }
        const float* bL = (L == 0) ? b0 : (L == 1) ? b1 : (L == 2) ? b2 : b3;
        const short8* bp = (const short8*)WB + t*512;   // 8KB quarter-layer stage
        #pragma unroll
        for (int nt = 0; nt < 2; ++nt) {
            floatx4 accA = {}, accB = {};
            #pragma unroll
            for (int c = 0; c < 4; ++c) {
                short8 bw = bp[(nt*4 + c)*64 + lane];
                accA = __builtin_amdgcn_mfma_f32_16x16x32_bf16(aA[c], bw, accA, 0, 0, 0);
                accB = __builtin_amdgcn_mfma_f32_16x16x32_bf16(aB[c], bw, accB, 0, 0, 0);
            }
            const int col = (q*2 + nt)*16 + ptl;
            const float bias = bL[col];
            #pragma unroll
            for (int r = 0; r < 4; ++r) {
                float hA = accA[r] + bias;
                float hB = accB[r] + bias;
                float sA = __sinf(hA);
                float sB = __sinf(hB);
                hA = 0.5f*hA + sA*sA;                   // SnakeAlt
                hB = 0.5f*hB + sB*sB;
                act[(wv*32 + quad*4 + r)*136 + col]      = f2bf(hA);
                act[(wv*32 + 16 + quad*4 + r)*136 + col] = f2bf(hB);
            }
        }
    }

    // ---------- layer 4: 128 -> 1 (W4 loads shared across both tiles) ----------
    float oA = 0.f, oB = 0.f;
    #pragma unroll
    for (int s = 0; s < 4; ++s) {
        short8 avA = *(const short8*)&act[myrowA + quad*32 + s*8];
        short8 avB = *(const short8*)&act[myrowB + quad*32 + s*8];
        const floatx4* wp = (const floatx4*)W4 + (quad*32 + s*8)/4;
        floatx4 w0 = wp[0], w1 = wp[1];
        oA = fmaf(bf2f((unsigned short)avA[0]), w0[0], oA);
        oB = fmaf(bf2f((unsigned short)avB[0]), w0[0], oB);
        oA = fmaf(bf2f((unsigned short)avA[1]), w0[1], oA);
        oB = fmaf(bf2f((unsigned short)avB[1]), w0[1], oB);
        oA = fmaf(bf2f((unsigned short)avA[2]), w0[2], oA);
        oB = fmaf(bf2f((unsigned short)avB[2]), w0[2], oB);
        oA = fmaf(bf2f((unsigned short)avA[3]), w0[3], oA);
        oB = fmaf(bf2f((unsigned short)avB[3]), w0[3], oB);
        oA = fmaf(bf2f((unsigned short)avA[4]), w1[0], oA);
        oB = fmaf(bf2f((unsigned short)avB[4]), w1[0], oB);
        oA = fmaf(bf2f((unsigned short)avA[5]), w1[1], oA);
        oB = fmaf(bf2f((unsigned short)avB[5]), w1[1], oB);
        oA = fmaf(bf2f((unsigned short)avA[6]), w1[2], oA);
        oB = fmaf(bf2f((unsigned short)avB[6]), w1[2], oB);
        oA = fmaf(bf2f((unsigned short)avA[7]), w1[3], oA);
        oB = fmaf(bf2f((unsigned short)avB[7]), w1[3], oB);
    }
    oA += __shfl_xor(oA, 16);
    oA += __shfl_xor(oA, 32);
    oB += __shfl_xor(oB, 16);
    oB += __shfl_xor(oB, 32);
    if (quad == 0) {
        float bb = b4[0];
        out[ptbase + ptl]      = oA + bb;
        out[ptbase + 16 + ptl] = oB + bb;
    }
}

extern "C" void kernel_launch(void* const* d_in, const int* in_sizes, int n_in,
                              void* d_out, int out_size, void* d_ws, size_t ws_size,
                              hipStream_t stream)
{
    const float* x  = (const float*)d_in[0];
    const float* lc = (const float*)d_in[1];
    const float* fv = (const float*)d_in[2];
    const float* W0 = (const float*)d_in[3];
    const float* b0 = (const float*)d_in[4];
    const float* W1 = (const float*)d_in[5];
    const float* b1 = (const float*)d_in[6];
    const float* W2 = (const float*)d_in[7];
    const float* b2 = (const float*)d_in[8];
    const float* W3 = (const float*)d_in[9];
    const float* b3 = (const float*)d_in[10];
    const float* W4 = (const float*)d_in[11];
    const float* b4 = (const float*)d_in[12];

    char* ws = (char*)d_ws;
    unsigned short* DBp = (unsigned short*)(ws + 0);                // 64 KB
    unsigned short* fvB = (unsigned short*)(ws + 65536);            // 128 KB
    unsigned short* WB  = (unsigned short*)(ws + 65536 + 131072);   // 128 KB

    prep_all<<<dim3(640), dim3(256), 0, stream>>>(lc, fv, W0, W1, W2, W3,
                                                  DBp, fvB, WB);

    afvsrn_mfma<<<dim3(N_PTS/128), dim3(256), 0, stream>>>(
        x, DBp, fvB, WB, b0, b1, b2, b3, W4, b4, (float*)d_out);
}

// Round 10
// 149.218 us; speedup vs baseline: 1.3539x; 1.0580x over previous
//
#include <hip/hip_runtime.h>
#include <hip/hip_bf16.h>

#define N_PTS   131072
#define N_FEATS 1000
#define FDIM    64
#define HID     128
#define NCHUNK  32          // 32 K-chunks of 32 features (padded 1000 -> 1024)
#define PI_F    3.14159265358979f
#define L2E     1.44269504f
#define EPS_D2  4e-7f       // in-MFMA d2 epsilon (K-slot 24); > split residual ~1e-7

typedef short  short8  __attribute__((ext_vector_type(8)));   // bf16 A/B frag (4 VGPRs)
typedef float  floatx4 __attribute__((ext_vector_type(4)));   // C/D frag

// ---- bf16 helpers ----
__device__ __forceinline__ unsigned int packbf2(float a, float b) {
    float2 t; t.x = a; t.y = b;
    __hip_bfloat162 h = __float22bfloat162_rn(t);
    union { __hip_bfloat162 hh; unsigned int u; } cv; cv.hh = h;
    return cv.u;
}
__device__ __forceinline__ unsigned short f2bf(float f) {      // RNE, 1 v_cvt_pk
    return (unsigned short)packbf2(f, f);
}
__device__ __forceinline__ float bf2f(unsigned short h) {
    return __uint_as_float(((unsigned int)h) << 16);
}
__device__ __forceinline__ floatx4 min3_4(floatx4 a, floatx4 b, floatx4 c) {
    floatx4 r;
    r[0] = fminf(fminf(a[0], b[0]), c[0]);
    r[1] = fminf(fminf(a[1], b[1]), c[1]);
    r[2] = fminf(fminf(a[2], b[2]), c[2]);
    r[3] = fminf(fminf(a[3], b[3]), c[3]);
    return r;
}
// p-pair: exp2(fma(rsq(d2), log2e, nm)) for two d2 values -> packed bf16x2.
// d2 > 0 guaranteed by the in-MFMA epsilon slot -> no fmax guard needed.
__device__ __forceinline__ unsigned int pack_p2(float d0, float d1, float nm) {
    float p0 = __builtin_amdgcn_exp2f(fmaf(__builtin_amdgcn_rsqf(d0), L2E, nm));
    float p1 = __builtin_amdgcn_exp2f(fmaf(__builtin_amdgcn_rsqf(d1), L2E, nm));
    return packbf2(p0, p1);
}

// ============================================================================
// d2 VIA MFMA. d2[f][p] = |loc_f|^2 - 2 loc_f . x_p + |x_p|^2 + EPS as K-dot:
// triple bf16 split (hi/mid/lo, ~24-bit effective) of both sides, 25 K-slots:
//   per dim d (slots d*6+t): A(loc)=[lh,lh,lm,lh,lm,ll], B(x)=[xh,xm,xh,xl,xm,xh]
//   slots 18..20: A=[SLh,SLm,SLl], B=1   (|loc|^2)
//   slots 21..23: A=1,            B=[Ah,Am,Al]  (|x|^2)
//   slot  24:     A=EPS_D2,       B=1   (positivity guard, kills fmax)
//   slots 25..31: 0
// Total d2 error ~1e-7 (fp32-class); d2 >= EPS-|err| > 0 always.
// Pass 1 and pass 2 issue the IDENTICAL mfma -> d2 bit-identical across passes.
// C-frag layout: col=lane&15=point, row=quad*4+r=feature.
// ============================================================================

// x-side (B operand) fragment: lane quad selects its 8 K-slots for its point.
__device__ __forceinline__ short8 xfrag_build(int quad, float x0, float x1, float x2) {
    unsigned short h0, m0, l0, h1, m1, l1, h2, m2, l2, Ah, Am, Al;
    { h0 = f2bf(x0); float r = x0 - bf2f(h0); m0 = f2bf(r); l0 = f2bf(r - bf2f(m0)); }
    { h1 = f2bf(x1); float r = x1 - bf2f(h1); m1 = f2bf(r); l1 = f2bf(r - bf2f(m1)); }
    { h2 = f2bf(x2); float r = x2 - bf2f(h2); m2 = f2bf(r); l2 = f2bf(r - bf2f(m2)); }
    float A = x0*x0 + x1*x1 + x2*x2;
    { Ah = f2bf(A); float r = A - bf2f(Ah); Am = f2bf(r); Al = f2bf(r - bf2f(Am)); }
    union { short8 v; unsigned short u[8]; } f;
    if (quad == 0) {        // slots 0..7: d0 t0..5, d1 t0..1
        f.u[0]=h0; f.u[1]=m0; f.u[2]=h0; f.u[3]=l0; f.u[4]=m0; f.u[5]=h0; f.u[6]=h1; f.u[7]=m1;
    } else if (quad == 1) { // slots 8..15: d1 t2..5, d2 t0..3
        f.u[0]=h1; f.u[1]=l1; f.u[2]=m1; f.u[3]=h1; f.u[4]=h2; f.u[5]=m2; f.u[6]=h2; f.u[7]=l2;
    } else if (quad == 2) { // slots 16..23: d2 t4..5, SL-pair ones, |x|^2 split
        f.u[0]=m2; f.u[1]=h2; f.u[2]=0x3F80; f.u[3]=0x3F80; f.u[4]=0x3F80; f.u[5]=Ah; f.u[6]=Am; f.u[7]=Al;
    } else {                // slot 24: 1.0 (pairs with A-side EPS), 25..31 zero
        f.v = (short8)0;
        f.u[0] = 0x3F80;
    }
    return f.v;
}

// ---------------- fused prep ----------------
// fvB: k-slot remap to match MFMA-computed p layout:
//   i = ((c*4+quad)*64 + n)*8 + j ; f = c*32 + ((j<4)? quad*4+j : 16+quad*4+(j-4))
// WB: 16 stages (4 layers x 4 quarters) of 8KB, lane-indexed:
//   r = ((((L*4+q)*2 + nt)*4 + c)*64 + lane)*8 + j
// DB: loc-side A-frags for the d2 MFMA. 64 fragsets (16 features each):
//   r = ((fg*4 + quad)*16 + ft)*8 + j ; feature f = fg*16+ft ; slot s = quad*8+j
//   pads (f >= N_FEATS) use loc = 1e9 -> d2 ~ 3e18, never the min.
__global__ void prep_all(const float* __restrict__ locs, const float* __restrict__ fv,
                         const float* __restrict__ W0, const float* __restrict__ W1,
                         const float* __restrict__ W2, const float* __restrict__ W3,
                         unsigned short* __restrict__ DB,
                         unsigned short* __restrict__ fvB, unsigned short* __restrict__ WB)
{
    int i = blockIdx.x * 256 + threadIdx.x;
    if (i < 65536) {
        int j = i & 7, n = (i >> 3) & 63, cq = i >> 9;
        int c = cq >> 2, quad = cq & 3;
        int fl = (j < 4) ? quad*4 + j : 16 + quad*4 + (j - 4);
        int f = c*32 + fl;
        float v = (f < N_FEATS) ? fv[f*FDIM + n] : 0.f;
        fvB[i] = f2bf(v);
    } else if (i < 131072) {
        int r = i - 65536;
        int j = r & 7, lane = (r >> 3) & 63, c = (r >> 9) & 3;
        int nt = (r >> 11) & 1, q = (r >> 12) & 3, L = r >> 14;
        int n = (q*2 + nt)*16 + (lane & 15);
        int k = c*32 + (lane >> 4)*8 + j;
        const float* W = (L == 0) ? W0 : (L == 1) ? W1 : (L == 2) ? W2 : W3;
        int Kin = (L == 0) ? 100 : 128;
        float v = (k < Kin) ? W[n*Kin + k] : 0.f;
        WB[r] = f2bf(v);
    } else if (i < 163840) {
        int r = i - 131072;
        int j = r & 7, ft = (r >> 3) & 15, quad = (r >> 7) & 3, fg = r >> 9;
        int f = fg*16 + ft, s = quad*8 + j;
        float lx, ly, lz;
        if (f < N_FEATS) { lx = locs[f*3+0]; ly = locs[f*3+1]; lz = locs[f*3+2]; }
        else             { lx = 1e9f; ly = 1e9f; lz = 1e9f; }
        unsigned short val = 0;
        if (s < 18) {
            int d = s / 6, t = s - d*6;
            float l2 = -2.f * ((d == 0) ? lx : (d == 1) ? ly : lz);
            unsigned short h = f2bf(l2);
            float r1 = l2 - bf2f(h);
            unsigned short m = f2bf(r1);
            unsigned short l = f2bf(r1 - bf2f(m));
            val = (t == 2 || t == 4) ? m : (t == 5) ? l : h;
        } else if (s < 21) {
            float SL = lx*lx + ly*ly + lz*lz;
            unsigned short h = f2bf(SL);
            float r1 = SL - bf2f(h);
            unsigned short m = f2bf(r1);
            unsigned short l = f2bf(r1 - bf2f(m));
            val = (s == 18) ? h : (s == 19) ? m : l;
        } else if (s < 24) {
            val = 0x3F80;          // 1.0 (pairs with B-side |x|^2 split)
        } else if (s == 24) {
            val = f2bf(EPS_D2);    // positivity epsilon (pairs with B-side 1.0)
        }
        DB[r] = val;
    }
}

// ---------------- main fused kernel ----------------
// 4 waves/block, 64 points/wave (FOUR 16-pt tiles: 4 independent trans chains
// per chunk; fvB/DB/WB/W4 loads and loop overhead amortized 4x). Zero barriers.
// launch_bounds(256,2): 2 blocks/CU, VGPR budget 256 (audit: ~80 acc + ~110
// arch peak ~ 190 -- 60+ headroom, no R5/R7-style squeeze). Grid 512 = exactly
// 2 blocks/CU x 256 CU: one perfectly balanced round, zero tail.
// LDS 69632 B/block x 2 = 139 KB <= 160 KB.
__global__ __launch_bounds__(256, 2)
void afvsrn_mfma(const float* __restrict__ x,
                 const unsigned short* __restrict__ DB,
                 const unsigned short* __restrict__ fvB,
                 const unsigned short* __restrict__ WB,
                 const float* __restrict__ b0, const float* __restrict__ b1,
                 const float* __restrict__ b2, const float* __restrict__ b3,
                 const float* __restrict__ W4, const float* __restrict__ b4,
                 float* __restrict__ out)
{
    __shared__ unsigned short act[256 * 136];                 // [256 pts][128+8 pad] bf16

    const int lane = threadIdx.x & 63;
    const int wv   = threadIdx.x >> 6;
    const int ptl  = lane & 15;
    const int quad = lane >> 4;
    const int ptbase = blockIdx.x * 256 + wv * 64;

    float x0[4], x1[4], x2[4];
    #pragma unroll
    for (int t = 0; t < 4; ++t) {
        x0[t] = x[(ptbase + t*16 + ptl)*3 + 0];
        x1[t] = x[(ptbase + t*16 + ptl)*3 + 1];
        x2[t] = x[(ptbase + t*16 + ptl)*3 + 2];
    }
    short8 xf[4];
    #pragma unroll
    for (int t = 0; t < 4; ++t) xf[t] = xfrag_build(quad, x0[t], x1[t], x2[t]);

    const short8* DBp = (const short8*)DB;
    const int dbidx = quad*16 + ptl;           // A-frag lane slot within a fragset
    const floatx4 Z = {0.f, 0.f, 0.f, 0.f};

    // ---------- pass 1: min d2 via MFMA (lane holds 8 features x its point) ----------
    floatx4 mn[4];
    #pragma unroll
    for (int t = 0; t < 4; ++t) { mn[t][0]=1e30f; mn[t][1]=1e30f; mn[t][2]=1e30f; mn[t][3]=1e30f; }
    #pragma unroll 2
    for (int c = 0; c < NCHUNK; ++c) {
        short8 a0 = DBp[(2*c    )*64 + dbidx];
        short8 a1 = DBp[(2*c + 1)*64 + dbidx];
        #pragma unroll
        for (int t = 0; t < 4; ++t) {
            floatx4 d0 = __builtin_amdgcn_mfma_f32_16x16x32_bf16(a0, xf[t], Z, 0, 0, 0);
            floatx4 d1 = __builtin_amdgcn_mfma_f32_16x16x32_bf16(a1, xf[t], Z, 0, 0, 0);
            mn[t] = min3_4(mn[t], d0, d1);
        }
    }
    float nm[4];
    #pragma unroll
    for (int t = 0; t < 4; ++t) {
        float md = fminf(fminf(mn[t][0], mn[t][1]), fminf(mn[t][2], mn[t][3]));
        md = fminf(md, __shfl_xor(md, 16));
        md = fminf(md, __shfl_xor(md, 32));
        // d2 > 0 guaranteed (EPS slot); pass 2 recomputes the SAME MFMA -> the
        // argmin element's d2 is bit-identical -> p_argmin = exp2(~0) ~ 1.
        nm[t] = -__builtin_amdgcn_rsqf(md) * L2E;
    }

    // ---------- pass 2: p = exp2(fma(rsq(d2), log2e, nm)); GEMM feats = p @ fv ----
    // p lands in C-frag layout (features quad*4+r per half) which maps straight
    // into the GEMM A-frag k-slots via the fvB remap (j<4: D0, j>=4: D1).
    // ls comes free from an extra MFMA vs all-ones B; its C row = the point
    // whose linv each lane needs -> no shuffles. Chunk 31 (pads) peeled.
    const short8 ONES = {0x3F80,0x3F80,0x3F80,0x3F80,0x3F80,0x3F80,0x3F80,0x3F80};
    floatx4 acc2[4][4] = {};
    floatx4 accL[4] = {};
    #pragma unroll 1
    for (int c = 0; c < NCHUNK-1; ++c) {
        const short8* bp = (const short8*)fvB + (c*4 + quad)*64;
        short8 bfv0 = bp[ptl];
        short8 bfv1 = bp[16 + ptl];
        short8 bfv2 = bp[32 + ptl];
        short8 bfv3 = bp[48 + ptl];
        short8 a0 = DBp[(2*c    )*64 + dbidx];
        short8 a1 = DBp[(2*c + 1)*64 + dbidx];
        #pragma unroll
        for (int t = 0; t < 4; ++t) {
            floatx4 d0 = __builtin_amdgcn_mfma_f32_16x16x32_bf16(a0, xf[t], Z, 0, 0, 0);
            floatx4 d1 = __builtin_amdgcn_mfma_f32_16x16x32_bf16(a1, xf[t], Z, 0, 0, 0);
            union { short8 v; unsigned int u[4]; } af;
            af.u[0] = pack_p2(d0[0], d0[1], nm[t]);
            af.u[1] = pack_p2(d0[2], d0[3], nm[t]);
            af.u[2] = pack_p2(d1[0], d1[1], nm[t]);
            af.u[3] = pack_p2(d1[2], d1[3], nm[t]);
            acc2[t][0] = __builtin_amdgcn_mfma_f32_16x16x32_bf16(af.v, bfv0, acc2[t][0], 0, 0, 0);
            acc2[t][1] = __builtin_amdgcn_mfma_f32_16x16x32_bf16(af.v, bfv1, acc2[t][1], 0, 0, 0);
            acc2[t][2] = __builtin_amdgcn_mfma_f32_16x16x32_bf16(af.v, bfv2, acc2[t][2], 0, 0, 0);
            acc2[t][3] = __builtin_amdgcn_mfma_f32_16x16x32_bf16(af.v, bfv3, acc2[t][3], 0, 0, 0);
            accL[t]    = __builtin_amdgcn_mfma_f32_16x16x32_bf16(af.v, ONES, accL[t], 0, 0, 0);
        }
    }
    {   // ---------- peeled chunk 31: features 992..1023 ----------
        // D0 half (992..1007): quads 0,1 real (992..999), quads 2,3 pad.
        // D1 half (1008..1023): all pad -> p = 0 (af slots 4..7 zeroed).
        const int c = NCHUNK-1;
        const short8* bp = (const short8*)fvB + (c*4 + quad)*64;
        short8 bfv0 = bp[ptl];
        short8 bfv1 = bp[16 + ptl];
        short8 bfv2 = bp[32 + ptl];
        short8 bfv3 = bp[48 + ptl];
        short8 a0 = DBp[(2*c)*64 + dbidx];
        #pragma unroll
        for (int t = 0; t < 4; ++t) {
            floatx4 d0 = __builtin_amdgcn_mfma_f32_16x16x32_bf16(a0, xf[t], Z, 0, 0, 0);
            const float nme = (quad < 2) ? nm[t] : -__builtin_inff();
            union { short8 v; unsigned int u[4]; } af;
            af.u[0] = pack_p2(d0[0], d0[1], nme);
            af.u[1] = pack_p2(d0[2], d0[3], nme);
            af.u[2] = 0; af.u[3] = 0;
            acc2[t][0] = __builtin_amdgcn_mfma_f32_16x16x32_bf16(af.v, bfv0, acc2[t][0], 0, 0, 0);
            acc2[t][1] = __builtin_amdgcn_mfma_f32_16x16x32_bf16(af.v, bfv1, acc2[t][1], 0, 0, 0);
            acc2[t][2] = __builtin_amdgcn_mfma_f32_16x16x32_bf16(af.v, bfv2, acc2[t][2], 0, 0, 0);
            acc2[t][3] = __builtin_amdgcn_mfma_f32_16x16x32_bf16(af.v, bfv3, acc2[t][3], 0, 0, 0);
            accL[t]    = __builtin_amdgcn_mfma_f32_16x16x32_bf16(af.v, ONES, accL[t], 0, 0, 0);
        }
    }

    float linv[4][4];
    #pragma unroll
    for (int t = 0; t < 4; ++t)
        #pragma unroll
        for (int r = 0; r < 4; ++r)
            linv[t][r] = __builtin_amdgcn_rcpf(accL[t][r]);

    // ---------- stage y = [PE(36) | feats(64) | zero pad to 128] for all tiles ----
    int myrow[4];
    #pragma unroll
    for (int t = 0; t < 4; ++t) {
        myrow[t] = (wv*64 + t*16 + ptl) * 136;
        *(short8*)&act[myrow[t] + 96 + quad*8] = (short8)0;
    }

    #pragma unroll
    for (int i = 0; i < 9; ++i) {
        int k = quad*9 + i;
        int d = k / 12, r12 = k % 12, l = r12 % 6;
        float fr = PI_F * (float)(1 << l);
        #pragma unroll
        for (int t = 0; t < 4; ++t) {
            float xv = (d == 0) ? x0[t] : (d == 1) ? x1[t] : x2[t];
            float v = (r12 < 6) ? __sinf(xv * fr) : __cosf(xv * fr);
            act[myrow[t] + k] = f2bf(v);
        }
    }

    #pragma unroll
    for (int nt = 0; nt < 4; ++nt)
        #pragma unroll
        for (int r = 0; r < 4; ++r)
            #pragma unroll
            for (int t = 0; t < 4; ++t)
                act[(wv*64 + t*16 + quad*4 + r)*136 + 36 + nt*16 + ptl] =
                    f2bf(acc2[t][nt][r] * linv[t][r]);

    // ---------- MLP layers 0..3 via MFMA, weights direct from L2 (no barriers) ----
    short8 a[4][4];
    #pragma unroll 1
    for (int st = 0; st < 16; ++st) {
        const int L = st >> 2, q = st & 3;
        if (q == 0) {      // new layer: capture input activations (wave-private rows)
            #pragma unroll
            for (int t = 0; t < 4; ++t)
                #pragma unroll
                for (int c = 0; c < 4; ++c)
                    a[t][c] = *(const short8*)&act[myrow[t] + c*32 + quad*8];
        }
        const float* bL = (L == 0) ? b0 : (L == 1) ? b1 : (L == 2) ? b2 : b3;
        const short8* bp = (const short8*)WB + st*512;   // 8KB quarter-layer stage
        #pragma unroll
        for (int nt = 0; nt < 2; ++nt) {
            floatx4 ac[4] = {};
            #pragma unroll
            for (int c = 0; c < 4; ++c) {
                short8 bw = bp[(nt*4 + c)*64 + lane];
                #pragma unroll
                for (int t = 0; t < 4; ++t)
                    ac[t] = __builtin_amdgcn_mfma_f32_16x16x32_bf16(a[t][c], bw, ac[t], 0, 0, 0);
            }
            const int col = (q*2 + nt)*16 + ptl;
            const float bias = bL[col];
            #pragma unroll
            for (int t = 0; t < 4; ++t)
                #pragma unroll
                for (int r = 0; r < 4; ++r) {
                    float h = ac[t][r] + bias;
                    float s = __sinf(h);
                    h = 0.5f*h + s*s;                   // SnakeAlt
                    act[(wv*64 + t*16 + quad*4 + r)*136 + col] = f2bf(h);
                }
        }
    }

    // ---------- layer 4: 128 -> 1 (W4 loads shared across all 4 tiles) ----------
    float o[4] = {0.f, 0.f, 0.f, 0.f};
    #pragma unroll
    for (int sg = 0; sg < 4; ++sg) {
        const floatx4* wp = (const floatx4*)W4 + (quad*32 + sg*8)/4;
        floatx4 w0 = wp[0], w1 = wp[1];
        #pragma unroll
        for (int t = 0; t < 4; ++t) {
            short8 av = *(const short8*)&act[myrow[t] + quad*32 + sg*8];
            o[t] = fmaf(bf2f((unsigned short)av[0]), w0[0], o[t]);
            o[t] = fmaf(bf2f((unsigned short)av[1]), w0[1], o[t]);
            o[t] = fmaf(bf2f((unsigned short)av[2]), w0[2], o[t]);
            o[t] = fmaf(bf2f((unsigned short)av[3]), w0[3], o[t]);
            o[t] = fmaf(bf2f((unsigned short)av[4]), w1[0], o[t]);
            o[t] = fmaf(bf2f((unsigned short)av[5]), w1[1], o[t]);
            o[t] = fmaf(bf2f((unsigned short)av[6]), w1[2], o[t]);
            o[t] = fmaf(bf2f((unsigned short)av[7]), w1[3], o[t]);
        }
    }
    #pragma unroll
    for (int t = 0; t < 4; ++t) {
        o[t] += __shfl_xor(o[t], 16);
        o[t] += __shfl_xor(o[t], 32);
    }
    if (quad == 0) {
        float bb = b4[0];
        #pragma unroll
        for (int t = 0; t < 4; ++t)
            out[ptbase + t*16 + ptl] = o[t] + bb;
    }
}

extern "C" void kernel_launch(void* const* d_in, const int* in_sizes, int n_in,
                              void* d_out, int out_size, void* d_ws, size_t ws_size,
                              hipStream_t stream)
{
    const float* x  = (const float*)d_in[0];
    const float* lc = (const float*)d_in[1];
    const float* fv = (const float*)d_in[2];
    const float* W0 = (const float*)d_in[3];
    const float* b0 = (const float*)d_in[4];
    const float* W1 = (const float*)d_in[5];
    const float* b1 = (const float*)d_in[6];
    const float* W2 = (const float*)d_in[7];
    const float* b2 = (const float*)d_in[8];
    const float* W3 = (const float*)d_in[9];
    const float* b3 = (const float*)d_in[10];
    const float* W4 = (const float*)d_in[11];
    const float* b4 = (const float*)d_in[12];

    char* ws = (char*)d_ws;
    unsigned short* DBp = (unsigned short*)(ws + 0);                // 64 KB
    unsigned short* fvB = (unsigned short*)(ws + 65536);            // 128 KB
    unsigned short* WB  = (unsigned short*)(ws + 65536 + 131072);   // 128 KB

    prep_all<<<dim3(640), dim3(256), 0, stream>>>(lc, fv, W0, W1, W2, W3,
                                                  DBp, fvB, WB);

    afvsrn_mfma<<<dim3(N_PTS/256), dim3(256), 0, stream>>>(
        x, DBp, fvB, WB, b0, b1, b2, b3, W4, b4, (float*)d_out);
}